// Round 13
// baseline (286.936 us; speedup 1.0000x reference)
//
#include <hip/hip_runtime.h>
#include <hip/hip_fp16.h>
#include <math.h>

#define IN_C   128
#define HEADS  4
#define F1     128   // HEADS*HID
#define OUT_C  32
#define NEG    0.2f
#define SH     8     // bucket = dst >> SH (256 dsts per bucket); needs n <= 2^17
#define CHA    8192  // edges per chunk in CSR pass A
#define SCB    4096  // elements per scan block (256 thr x 16)

// ---- fp16 helpers (RNE) ----
__device__ __forceinline__ unsigned short f2h(float f) {
    return __half_as_ushort(__float2half_rn(f));
}
__device__ __forceinline__ float h2f(unsigned short u) {
    return __half2float(__ushort_as_half(u));
}
__device__ __forceinline__ float hlo(unsigned u) { return h2f((unsigned short)(u & 0xffffu)); }
__device__ __forceinline__ float hhi(unsigned u) { return h2f((unsigned short)(u >> 16)); }
__device__ __forceinline__ unsigned pk2(float a, float b) {
    return (unsigned)f2h(a) | ((unsigned)f2h(b) << 16);
}
typedef _Float16 h2v  __attribute__((ext_vector_type(2)));
typedef _Float16 f16x4v __attribute__((ext_vector_type(4)));
typedef _Float16 f16x8v __attribute__((ext_vector_type(8)));
typedef float    f32x4v __attribute__((ext_vector_type(4)));
__device__ __forceinline__ h2v u2h2(unsigned u) {
    h2v r; __builtin_memcpy(&r, &u, 4); return r;
}
__device__ __forceinline__ float dot2(unsigned a, unsigned b, float c) {
    return __builtin_amdgcn_fdot2(u2h2(a), u2h2(b), c, false);
}
// v_perm: D = (A.lo16, B.lo16) with perm(B, A, PERM_LO)  [A -> low half]
#define PERM_LO 0x05040100u
#define PERM_HI 0x07060302u
__device__ __forceinline__ float pdot(unsigned b, unsigned a, unsigned sel, h2v pv, float c) {
    return __builtin_amdgcn_fdot2(u2h2(__builtin_amdgcn_perm(b, a, sel)), pv, c, false);
}

// ============ pre-pass: W1 -> packed B fragments (once, 32 KB global) ========
// Same frag-lane mapping as the R12-verified in-kernel staging: frag f=(s*8+ct),
// lane l holds W[k0+j][col], j=0..7, col=ct*16+(l&15), k0=s*32+(l>>4)*8.
// Uncoalesced transpose runs ONCE here instead of in all gemm blocks.
__global__ __launch_bounds__(256) void k_prepW(
    const float* __restrict__ W, uint4* __restrict__ bfg)
{
    int i = blockIdx.x * 256 + threadIdx.x;   // frag-lane id, 2048 total
    if (i >= 2048) return;
    int f = i >> 6, l = i & 63;
    int s = f >> 3, ct = f & 7;
    int col = ct * 16 + (l & 15);
    int k0 = s * 32 + (l >> 4) * 8;
    const float* wp = &W[(size_t)k0 * 128 + col];
    unsigned short u0 = f2h(wp[0]);
    unsigned short u1 = f2h(wp[128]);
    unsigned short u2 = f2h(wp[256]);
    unsigned short u3 = f2h(wp[384]);
    unsigned short u4 = f2h(wp[512]);
    unsigned short u5 = f2h(wp[640]);
    unsigned short u6 = f2h(wp[768]);
    unsigned short u7 = f2h(wp[896]);
    uint4 p;
    p.x = (unsigned)u0 | ((unsigned)u1 << 16);
    p.y = (unsigned)u2 | ((unsigned)u3 << 16);
    p.z = (unsigned)u4 | ((unsigned)u5 << 16);
    p.w = (unsigned)u6 | ((unsigned)u7 << 16);
    bfg[i] = p;
}

// ============ fused: CSR pass A1 (bucket histogram) ∥ layer-1 MFMA GEMM ======
// blockIdx < NC  -> bhist role (LDS atomic histogram into bmat[bucket][chunk])
// else           -> gemm role: h1 = x@W1 via v_mfma_f32_16x16x32_f16.
//   B fragments loaded from precomputed bfg (coalesced 32 KB linear copy,
//   L2-resident) -> K-loop B reads are linear b128, conflict-free.
__global__ __launch_bounds__(256) void k_gemm1m(
    const float* __restrict__ x, const uint4* __restrict__ bfg,
    const float* __restrict__ as_w, const float* __restrict__ ad_w,
    const int* __restrict__ ei, int* __restrict__ bmat,
    unsigned short* __restrict__ h1h, float* __restrict__ as1,
    float* __restrict__ ad1, int n, int E_, int NB, int NC)
{
    __shared__ char lds[49152];
    int t = threadIdx.x;

    if ((int)blockIdx.x < NC) {          // ---- bhist role ----
        int* h = (int*)lds;
        int c = blockIdx.x;
        for (int i = t; i < NB; i += 256) h[i] = 0;
        __syncthreads();
        int e0 = c * CHA, e1 = min(e0 + CHA, E_ + n);
        for (int e = e0 + t; e < e1; e += 256) {
            int d = (e < E_) ? ei[E_ + e] : e - E_;
            atomicAdd(&h[d >> SH], 1);
        }
        __syncthreads();
        for (int i = t; i < NB; i += 256) bmat[i * NC + c] = h[i];
        return;
    }

    // ---- gemm role ----
    char* xhB = lds;               // 16 KB: x/h tile [64 rows][128 f16], XOR-swizzled
    char* bfB = lds + 16384;       // 32 KB: Bf[32 frags][64 lanes][16 B]
    int n0 = ((int)blockIdx.x - NC) * 64;

    // stage x tile fp16 (coalesced float4 reads, vector 8B LDS stores)
    for (int i = t; i < 64 * 32; i += 256) {
        int node = i >> 5, k4 = (i & 31) * 4;
        int nn = n0 + node;
        float4 v = (nn < n) ? *(const float4*)&x[(size_t)nn * 128 + k4]
                            : make_float4(0.f, 0.f, 0.f, 0.f);
        f16x4v hv = { (_Float16)v.x, (_Float16)v.y, (_Float16)v.z, (_Float16)v.w };
        *(f16x4v*)(xhB + node * 256 + ((2 * k4) ^ ((node & 7) << 4))) = hv;
    }
    // stage B fragments: coalesced linear copy of precomputed bfg (32 KB)
    for (int i = t; i < 2048; i += 256)
        *(uint4*)(bfB + (size_t)i * 16) = bfg[i];
    __syncthreads();

    int w = t >> 6, l = t & 63, g = l >> 4, cl = l & 15;
    int arow = w * 16 + cl;            // A row (local) for this lane
    f32x4v acc[8] = {};
    #pragma unroll
    for (int s = 0; s < 4; ++s) {
        int k2 = 2 * (s * 32 + g * 8);
        f16x8v a = *(f16x8v*)(xhB + arow * 256 + (k2 ^ ((arow & 7) << 4)));
        #pragma unroll
        for (int ct = 0; ct < 8; ++ct) {
            f16x8v b = *(f16x8v*)(bfB + ((s * 8 + ct) * 64 + l) * 16);
            acc[ct] = __builtin_amdgcn_mfma_f32_16x16x32_f16(a, b, acc[ct], 0, 0, 0);
        }
    }

    // fused attention partials (D: col=lane&15, row=g*4+r) — R8-verified
    #pragma unroll
    for (int h = 0; h < 4; ++h) {
        float asw0 = as_w[h * 32 + cl],      adw0 = ad_w[h * 32 + cl];
        float asw1 = as_w[h * 32 + 16 + cl], adw1 = ad_w[h * 32 + 16 + cl];
        float ps[4], pd[4];
        #pragma unroll
        for (int r = 0; r < 4; ++r) {
            ps[r] = acc[2 * h][r] * asw0 + acc[2 * h + 1][r] * asw1;
            pd[r] = acc[2 * h][r] * adw0 + acc[2 * h + 1][r] * adw1;
        }
        #pragma unroll
        for (int o = 1; o < 16; o <<= 1) {
            #pragma unroll
            for (int r = 0; r < 4; ++r) {
                ps[r] += __shfl_xor(ps[r], o);
                pd[r] += __shfl_xor(pd[r], o);
            }
        }
        if (cl == h) {
            #pragma unroll
            for (int r = 0; r < 4; ++r) {
                int node = n0 + w * 16 + g * 4 + r;
                if (node < n) {
                    as1[(size_t)node * 4 + h] = ps[r];
                    ad1[(size_t)node * 4 + h] = pd[r];
                }
            }
        }
    }

    // h1 -> LDS (own-wave rows; x-tile fully consumed), then 16B global stores
    #pragma unroll
    for (int tt = 0; tt < 8; ++tt) {
        int cc = tt * 16 + cl;
        #pragma unroll
        for (int r = 0; r < 4; ++r) {
            int rl = w * 16 + g * 4 + r;
            *(_Float16*)(xhB + rl * 256 + ((2 * cc) ^ ((rl & 7) << 4))) = (_Float16)acc[tt][r];
        }
    }
    __threadfence_block();
    int rl = w * 16 + cl;
    int node = n0 + rl;
    if (node < n) {
        #pragma unroll
        for (int i = 0; i < 4; ++i) {
            int slot = g * 4 + i;
            uint4 val = *(uint4*)(xhB + rl * 256 + slot * 16);
            int c0 = 8 * (slot ^ (rl & 7));
            *(uint4*)&h1h[(size_t)node * 128 + c0] = val;
        }
    }
}

// ============ CSR pass A2: parallel exclusive scan of bmat ===================
__global__ __launch_bounds__(256) void k_scanA(
    int* __restrict__ bmat, int* __restrict__ bsums, int M)
{
    __shared__ int sm[256];
    int t = threadIdx.x;
    int base = blockIdx.x * SCB + t * 16;
    int v[16];
    int s = 0;
    #pragma unroll
    for (int j = 0; j < 16; ++j) {
        int i = base + j;
        v[j] = (i < M) ? bmat[i] : 0;
        s += v[j];
    }
    sm[t] = s;
    __syncthreads();
    for (int off = 1; off < 256; off <<= 1) {
        int a = (t >= off) ? sm[t - off] : 0;
        __syncthreads();
        sm[t] += a;
        __syncthreads();
    }
    int excl = sm[t] - s;
    #pragma unroll
    for (int j = 0; j < 16; ++j) {
        int i = base + j;
        if (i < M) bmat[i] = excl;
        excl += v[j];
    }
    if (t == 255) bsums[blockIdx.x] = sm[255];
}

// ============ CSR pass A3: scatter packed recs into (bucket,chunk) ranges =====
__global__ __launch_bounds__(256) void k_bscatter(
    const int* __restrict__ ei, const int* __restrict__ bmat,
    const int* __restrict__ bsums, unsigned* __restrict__ recs,
    int E_, int n, int NB, int NC, int NBLK)
{
    __shared__ int cur[512];
    __shared__ int pref[32];
    int t = threadIdx.x, c = blockIdx.x;
    if (t < 32) {                     // exclusive prefix of bsums (<=32 entries)
        int v0 = (t < NBLK) ? bsums[t] : 0;
        int v = v0;
        #pragma unroll
        for (int o = 1; o < 32; o <<= 1) {
            int u = __shfl_up(v, o);
            if (t >= o) v += u;
        }
        pref[t] = v - v0;
    }
    __syncthreads();
    for (int i = t; i < NB; i += 256) {
        int m = i * NC + c;
        cur[i] = bmat[m] + pref[m >> 12];
    }
    __syncthreads();
    int e0 = c * CHA, e1 = min(e0 + CHA, E_ + n);
    for (int e = e0 + t; e < e1; e += 256) {
        int s, d;
        if (e < E_) { s = ei[e]; d = ei[E_ + e]; } else { s = d = e - E_; }
        int b = d >> SH;
        int p = atomicAdd(&cur[b], 1);   // LDS atomic
        recs[p] = ((unsigned)(d & ((1 << SH) - 1)) << 17) | (unsigned)s;
    }
}

// ============ CSR pass B: per-bucket fine fill (one block owns one bucket) ====
__global__ __launch_bounds__(256) void k_bfill(
    const unsigned* __restrict__ recs, const int* __restrict__ bmat,
    const int* __restrict__ bsums, int* __restrict__ row_off,
    int* __restrict__ csr, int n, int NB, int NC, int EE, int NBLK)
{
    __shared__ int deg[256];
    __shared__ int cur[256];
    __shared__ int pref[32];
    int t = threadIdx.x, b = blockIdx.x;
    if (t < 32) {
        int v0 = (t < NBLK) ? bsums[t] : 0;
        int v = v0;
        #pragma unroll
        for (int o = 1; o < 32; o <<= 1) {
            int u = __shfl_up(v, o);
            if (t >= o) v += u;
        }
        pref[t] = v - v0;
    }
    deg[t] = 0;
    __syncthreads();
    int m0 = b * NC;
    int r0 = bmat[m0] + pref[m0 >> 12];
    int r1 = EE;
    if (b + 1 < NB) {
        int m1 = (b + 1) * NC;
        r1 = bmat[m1] + pref[m1 >> 12];
    }
    for (int i = r0 + t; i < r1; i += 256)
        atomicAdd(&deg[recs[i] >> 17], 1);
    __syncthreads();
    int v = deg[t];
    for (int off = 1; off < 256; off <<= 1) {
        int a = (t >= off) ? deg[t - off] : 0;
        __syncthreads();
        deg[t] += a;
        __syncthreads();
    }
    int excl = deg[t] - v;
    int dst = (b << SH) + t;
    if (dst < n) row_off[dst] = r0 + excl;
    cur[t] = excl;
    if (b == NB - 1 && t == 0) row_off[n] = EE;
    __syncthreads();
    for (int i = r0 + t; i < r1; i += 256) {
        unsigned rec = recs[i];
        int dl = rec >> 17;
        int p = atomicAdd(&cur[dl], 1);   // LDS atomic
        csr[r0 + p] = (int)(rec & 0x1FFFFu);
    }
}

// ====== fused layer-1 GAT + layer-2 GEMM: softmax/gather/ELU + h2=z@W2 =======
// 16 lanes per node, 16 nodes per block; lane owns 8 z-channels (one head).
// Chunk=32; staged 4-PAIR gather; epilogue h2=z@W2 with z never touching HBM.
__global__ __launch_bounds__(256) void k_gat1(
    const int* __restrict__ row_off, const int* __restrict__ csr,
    const float* __restrict__ as1, const float* __restrict__ ad1,
    const unsigned short* __restrict__ h1h, const float* __restrict__ b1,
    const float* __restrict__ W2, const float* __restrict__ as2w,
    const float* __restrict__ ad2w, unsigned short* __restrict__ h2h,
    float* __restrict__ as2, float* __restrict__ ad2, int n)
{
    __shared__ int      s_src[16][36];     // 2.25 KB, byte offsets
    __shared__ unsigned s_pw[16][4][17];   // 4.25 KB, [node][head][pair-word]
    __shared__ unsigned W2s[64 * 32];      // 8 KB, [k2][col] packed pairs
    __shared__ unsigned zs[16][66];        // 4.1 KB, z rows packed (pad 66)
    int t = threadIdx.x;

    for (int i = t; i < 64 * 8; i += 256) {
        int k2 = i >> 3, c4 = (i & 7) * 4;
        float4 a = *(const float4*)&W2[(2 * k2) * 32 + c4];
        float4 b = *(const float4*)&W2[(2 * k2 + 1) * 32 + c4];
        uint4 p;
        p.x = pk2(a.x, b.x); p.y = pk2(a.y, b.y);
        p.z = pk2(a.z, b.z); p.w = pk2(a.w, b.w);
        *(uint4*)&W2s[k2 * 32 + c4] = p;
    }
    __syncthreads();

    int nb = t >> 4;                // node slot in block (0..15)
    int hl = t & 15;                // lane within node
    int node = blockIdx.x * 16 + nb;
    if (node < n) {
        int* ssrc = s_src[nb];
        unsigned (*spw)[17] = s_pw[nb];

        const char* h1b = (const char*)h1h;
        int chb  = hl << 4;         // byte offset of my 8 channels (8 * 2B)
        int head = hl >> 2;         // my head (channels hl*8 .. hl*8+7)

        float4 addv = *(const float4*)&ad1[(size_t)node * 4];
        int beg = row_off[node], end = row_off[node + 1];

        float sr0 = 0.f, sr1 = 0.f, sr2 = 0.f, sr3 = 0.f;
        float acc0 = 0.f, acc1 = 0.f, acc2 = 0.f, acc3 = 0.f;
        float acc4 = 0.f, acc5 = 0.f, acc6 = 0.f, acc7 = 0.f;

        for (int c = beg; c < end; c += 32) {
            int cnt = min(32, end - c);
            int e0 = hl << 1;       // this lane's 2 edges
            float ls0 = 0.f, ls1 = 0.f, ls2 = 0.f, ls3 = 0.f;
            if (e0 < cnt) {
                int sA = csr[c + e0];
                ssrc[e0] = sA << 8;
                float4 avA = *(const float4*)(as1 + ((unsigned)sA << 2));
                float v;
                unsigned short qa0, qa1, qa2, qa3;
                unsigned short qb0 = 0, qb1 = 0, qb2 = 0, qb3 = 0;
                v = avA.x + addv.x; v = v > 0.f ? v : NEG * v; qa0 = f2h(__expf(fminf(v, 10.f)));
                v = avA.y + addv.y; v = v > 0.f ? v : NEG * v; qa1 = f2h(__expf(fminf(v, 10.f)));
                v = avA.z + addv.z; v = v > 0.f ? v : NEG * v; qa2 = f2h(__expf(fminf(v, 10.f)));
                v = avA.w + addv.w; v = v > 0.f ? v : NEG * v; qa3 = f2h(__expf(fminf(v, 10.f)));
                if (e0 + 1 < cnt) {
                    int sB = csr[c + e0 + 1];
                    ssrc[e0 + 1] = sB << 8;
                    float4 avB = *(const float4*)(as1 + ((unsigned)sB << 2));
                    v = avB.x + addv.x; v = v > 0.f ? v : NEG * v; qb0 = f2h(__expf(fminf(v, 10.f)));
                    v = avB.y + addv.y; v = v > 0.f ? v : NEG * v; qb1 = f2h(__expf(fminf(v, 10.f)));
                    v = avB.z + addv.z; v = v > 0.f ? v : NEG * v; qb2 = f2h(__expf(fminf(v, 10.f)));
                    v = avB.w + addv.w; v = v > 0.f ? v : NEG * v; qb3 = f2h(__expf(fminf(v, 10.f)));
                }
                spw[0][hl] = (unsigned)qa0 | ((unsigned)qb0 << 16);
                spw[1][hl] = (unsigned)qa1 | ((unsigned)qb1 << 16);
                spw[2][hl] = (unsigned)qa2 | ((unsigned)qb2 << 16);
                spw[3][hl] = (unsigned)qa3 | ((unsigned)qb3 << 16);
                ls0 = h2f(qa0) + h2f(qb0);
                ls1 = h2f(qa1) + h2f(qb1);
                ls2 = h2f(qa2) + h2f(qb2);
                ls3 = h2f(qa3) + h2f(qb3);
            }
            #pragma unroll
            for (int o = 8; o; o >>= 1) {
                ls0 += __shfl_xor(ls0, o);
                ls1 += __shfl_xor(ls1, o);
                ls2 += __shfl_xor(ls2, o);
                ls3 += __shfl_xor(ls3, o);
            }
            sr0 += ls0; sr1 += ls1; sr2 += ls2; sr3 += ls3;
            __threadfence_block();

            #define MAC8(A, B, pw) {                                          \
                h2v pv = u2h2(pw);                                            \
                acc0 = pdot(B.x, A.x, PERM_LO, pv, acc0);                     \
                acc1 = pdot(B.x, A.x, PERM_HI, pv, acc1);                     \
                acc2 = pdot(B.y, A.y, PERM_LO, pv, acc2);                     \
                acc3 = pdot(B.y, A.y, PERM_HI, pv, acc3);                     \
                acc4 = pdot(B.z, A.z, PERM_LO, pv, acc4);                     \
                acc5 = pdot(B.z, A.z, PERM_HI, pv, acc5);                     \
                acc6 = pdot(B.w, A.w, PERM_LO, pv, acc6);                     \
                acc7 = pdot(B.w, A.w, PERM_HI, pv, acc7);                     \
            }
            int j = 0;
            for (; j + 8 <= cnt; j += 8) {
                int2 o0 = *(const int2*)&ssrc[j];
                int2 o1 = *(const int2*)&ssrc[j + 2];
                int2 o2 = *(const int2*)&ssrc[j + 4];
                int2 o3 = *(const int2*)&ssrc[j + 6];
                int w0 = j >> 1;
                unsigned pw0 = spw[head][w0];
                unsigned pw1 = spw[head][w0 + 1];
                unsigned pw2 = spw[head][w0 + 2];
                unsigned pw3 = spw[head][w0 + 3];
                uint4 A0 = *(const uint4*)(h1b + (unsigned)(o0.x + chb));
                uint4 B0 = *(const uint4*)(h1b + (unsigned)(o0.y + chb));
                uint4 A1 = *(const uint4*)(h1b + (unsigned)(o1.x + chb));
                uint4 B1 = *(const uint4*)(h1b + (unsigned)(o1.y + chb));
                uint4 A2 = *(const uint4*)(h1b + (unsigned)(o2.x + chb));
                uint4 B2 = *(const uint4*)(h1b + (unsigned)(o2.y + chb));
                uint4 A3 = *(const uint4*)(h1b + (unsigned)(o3.x + chb));
                uint4 B3 = *(const uint4*)(h1b + (unsigned)(o3.y + chb));
                MAC8(A0, B0, pw0);
                MAC8(A1, B1, pw1);
                MAC8(A2, B2, pw2);
                MAC8(A3, B3, pw3);
            }
            for (; j + 2 <= cnt; j += 2) {
                int2 oo = *(const int2*)&ssrc[j];
                unsigned pw = spw[head][j >> 1];
                uint4 A = *(const uint4*)(h1b + (unsigned)(oo.x + chb));
                uint4 B = *(const uint4*)(h1b + (unsigned)(oo.y + chb));
                MAC8(A, B, pw);
            }
            if (j < cnt) {
                int o0 = ssrc[j];
                float p = hlo(spw[head][j >> 1]);
                uint4 A = *(const uint4*)(h1b + (unsigned)(o0 + chb));
                acc0 = fmaf(p, hlo(A.x), acc0);
                acc1 = fmaf(p, hhi(A.x), acc1);
                acc2 = fmaf(p, hlo(A.y), acc2);
                acc3 = fmaf(p, hhi(A.y), acc3);
                acc4 = fmaf(p, hlo(A.z), acc4);
                acc5 = fmaf(p, hhi(A.z), acc5);
                acc6 = fmaf(p, hlo(A.w), acc6);
                acc7 = fmaf(p, hhi(A.w), acc7);
            }
            #undef MAC8
        }
        float srh = head == 0 ? sr0 : head == 1 ? sr1 : head == 2 ? sr2 : sr3;
        float inv = 1.0f / srh;
        float4 bb0 = *(const float4*)&b1[hl * 8];
        float4 bb1 = *(const float4*)&b1[hl * 8 + 4];
        float v0 = acc0 * inv + bb0.x;
        float v1 = acc1 * inv + bb0.y;
        float v2 = acc2 * inv + bb0.z;
        float v3 = acc3 * inv + bb0.w;
        float v4 = acc4 * inv + bb1.x;
        float v5 = acc5 * inv + bb1.y;
        float v6 = acc6 * inv + bb1.z;
        float v7 = acc7 * inv + bb1.w;
        v0 = v0 > 0.f ? v0 : (__expf(v0) - 1.f);
        v1 = v1 > 0.f ? v1 : (__expf(v1) - 1.f);
        v2 = v2 > 0.f ? v2 : (__expf(v2) - 1.f);
        v3 = v3 > 0.f ? v3 : (__expf(v3) - 1.f);
        v4 = v4 > 0.f ? v4 : (__expf(v4) - 1.f);
        v5 = v5 > 0.f ? v5 : (__expf(v5) - 1.f);
        v6 = v6 > 0.f ? v6 : (__expf(v6) - 1.f);
        v7 = v7 > 0.f ? v7 : (__expf(v7) - 1.f);

        // ---- fused layer-2 GEMM epilogue: h2 = z @ W2 (z never hits HBM) ----
        unsigned* zrow = zs[nb];
        zrow[hl * 4 + 0] = pk2(v0, v1);
        zrow[hl * 4 + 1] = pk2(v2, v3);
        zrow[hl * 4 + 2] = pk2(v4, v5);
        zrow[hl * 4 + 3] = pk2(v6, v7);
        __threadfence_block();
        int c0 = hl * 2;            // my 2 output columns
        float a0 = 0.f, a1 = 0.f;
        #pragma unroll 8
        for (int k2 = 0; k2 < 64; ++k2) {
            unsigned zp = zrow[k2];
            uint2 wp = *(const uint2*)&W2s[k2 * 32 + c0];
            a0 = dot2(zp, wp.x, a0);
            a1 = dot2(zp, wp.y, a1);
        }
        *(unsigned*)&h2h[(size_t)node * 32 + c0] = pk2(a0, a1);
        float2 asw = *(const float2*)&as2w[c0];
        float2 adw = *(const float2*)&ad2w[c0];
        float sa = a0 * asw.x + a1 * asw.y;
        float sd = a0 * adw.x + a1 * adw.y;
        #pragma unroll
        for (int o = 8; o; o >>= 1) {
            sa += __shfl_xor(sa, o);
            sd += __shfl_xor(sd, o);
        }
        if (hl == 0) { as2[node] = sa; ad2[node] = sd; }
    }
}

// ============ fused layer-2 GAT + log_softmax: 4 lanes/node, 64 nodes/block ===
__global__ __launch_bounds__(256) void k_gat2(
    const int* __restrict__ row_off, const int* __restrict__ csr,
    const float* __restrict__ as2, const float* __restrict__ ad2,
    const unsigned short* __restrict__ h2h, const float* __restrict__ b2,
    float* __restrict__ y, int n)
{
    int nb = threadIdx.x >> 2;      // node slot in block (0..63)
    int hl = threadIdx.x & 3;       // lane within node
    int node = blockIdx.x * 64 + nb;
    if (node >= n) return;
    __shared__ int            s_src[64][34];   // 8.5 KB, row BYTE offsets (src<<6)
    __shared__ unsigned short s_p16[64][34];   // 4.25 KB fp16 p
    int* ssrc = s_src[nb];
    unsigned short* sp16 = s_p16[nb];

    const char* h2b = (const char*)h2h;
    int chb = hl << 4;              // byte offset of my 8 channels (8 * 2B)

    float addv = ad2[node];
    int beg = row_off[node], end = row_off[node + 1];
    float sr = 0.f;
    float acc0 = 0.f, acc1 = 0.f, acc2 = 0.f, acc3 = 0.f;
    float acc4 = 0.f, acc5 = 0.f, acc6 = 0.f, acc7 = 0.f;

    for (int c = beg; c < end; c += 32) {
        int cnt = min(32, end - c);
        int e0 = hl << 3;           // 8 edges per lane
        float ls = 0.f;
        #pragma unroll
        for (int k = 0; k < 8; k += 2) {
            int e = e0 + k;
            if (e < cnt) {
                unsigned short qa, qb = 0;
                int sA = csr[c + e];
                ssrc[e] = sA << 6;  // byte offset of fp16 row (32 ch * 2B)
                float v = as2[(unsigned)sA] + addv;
                v = v > 0.f ? v : NEG * v;
                qa = f2h(__expf(fminf(v, 10.f)));
                if (e + 1 < cnt) {
                    int sB = csr[c + e + 1];
                    ssrc[e + 1] = sB << 6;
                    float w2 = as2[(unsigned)sB] + addv;
                    w2 = w2 > 0.f ? w2 : NEG * w2;
                    qb = f2h(__expf(fminf(w2, 10.f)));
                }
                *(unsigned*)&sp16[e] = (unsigned)qa | ((unsigned)qb << 16);
                ls += h2f(qa) + h2f(qb);
            }
        }
        ls += __shfl_xor(ls, 1);
        ls += __shfl_xor(ls, 2);
        sr += ls;
        __threadfence_block();

        #define PAIR2(j) {                                                    \
            int2 oo = *(const int2*)&ssrc[j];                                 \
            unsigned pp = *(const unsigned*)&sp16[j];                         \
            uint4 A = *(const uint4*)(h2b + (unsigned)(oo.x + chb));          \
            uint4 B = *(const uint4*)(h2b + (unsigned)(oo.y + chb));          \
            h2v pv = u2h2(pp);                                                \
            acc0 = pdot(B.x, A.x, PERM_LO, pv, acc0);                         \
            acc1 = pdot(B.x, A.x, PERM_HI, pv, acc1);                         \
            acc2 = pdot(B.y, A.y, PERM_LO, pv, acc2);                         \
            acc3 = pdot(B.y, A.y, PERM_HI, pv, acc3);                         \
            acc4 = pdot(B.z, A.z, PERM_LO, pv, acc4);                         \
            acc5 = pdot(B.z, A.z, PERM_HI, pv, acc5);                         \
            acc6 = pdot(B.w, A.w, PERM_LO, pv, acc6);                         \
            acc7 = pdot(B.w, A.w, PERM_HI, pv, acc7);                         \
        }
        int jj = 0;
        for (; jj + 4 <= cnt; jj += 4) {
            PAIR2(jj);
            PAIR2(jj + 2);
        }
        if (jj + 2 <= cnt) {
            PAIR2(jj);
            jj += 2;
        }
        if (jj < cnt) {
            int o0 = ssrc[jj];
            float p = h2f(sp16[jj]);
            uint4 A = *(const uint4*)(h2b + (unsigned)(o0 + chb));
            acc0 = fmaf(p, hlo(A.x), acc0);
            acc1 = fmaf(p, hhi(A.x), acc1);
            acc2 = fmaf(p, hlo(A.y), acc2);
            acc3 = fmaf(p, hhi(A.y), acc3);
            acc4 = fmaf(p, hlo(A.z), acc4);
            acc5 = fmaf(p, hhi(A.z), acc5);
            acc6 = fmaf(p, hlo(A.w), acc6);
            acc7 = fmaf(p, hhi(A.w), acc7);
        }
        #undef PAIR2
    }
    float inv = 1.0f / sr;
    float4 bb0 = *(const float4*)&b2[hl * 8];
    float4 bb1 = *(const float4*)&b2[hl * 8 + 4];
    float v0 = acc0 * inv + bb0.x;
    float v1 = acc1 * inv + bb0.y;
    float v2 = acc2 * inv + bb0.z;
    float v3 = acc3 * inv + bb0.w;
    float v4 = acc4 * inv + bb1.x;
    float v5 = acc5 * inv + bb1.y;
    float v6 = acc6 * inv + bb1.z;
    float v7 = acc7 * inv + bb1.w;
    float m = fmaxf(fmaxf(fmaxf(v0, v1), fmaxf(v2, v3)),
                    fmaxf(fmaxf(v4, v5), fmaxf(v6, v7)));
    m = fmaxf(m, __shfl_xor(m, 1));
    m = fmaxf(m, __shfl_xor(m, 2));
    float ss = __expf(v0 - m) + __expf(v1 - m) + __expf(v2 - m) + __expf(v3 - m)
             + __expf(v4 - m) + __expf(v5 - m) + __expf(v6 - m) + __expf(v7 - m);
    ss += __shfl_xor(ss, 1);
    ss += __shfl_xor(ss, 2);
    float lg = m + logf(ss);
    float* yr = &y[(size_t)node * OUT_C + hl * 8];
    *(float4*)yr       = make_float4(v0 - lg, v1 - lg, v2 - lg, v3 - lg);
    *(float4*)(yr + 4) = make_float4(v4 - lg, v5 - lg, v6 - lg, v7 - lg);
}

extern "C" void kernel_launch(void* const* d_in, const int* in_sizes, int n_in,
                              void* d_out, int out_size, void* d_ws, size_t ws_size,
                              hipStream_t stream) {
    const float* x    = (const float*)d_in[0];
    const int*   ei   = (const int*)d_in[1];
    const float* W1   = (const float*)d_in[2];
    const float* as1w = (const float*)d_in[3];
    const float* ad1w = (const float*)d_in[4];
    const float* b1   = (const float*)d_in[5];
    const float* W2   = (const float*)d_in[6];
    const float* as2w = (const float*)d_in[7];
    const float* ad2w = (const float*)d_in[8];
    const float* b2   = (const float*)d_in[9];
    float* out = (float*)d_out;

    int n  = in_sizes[0] / IN_C;
    int E_ = in_sizes[1] / 2;
    int EE = E_ + n;

    int NB = (n + (1 << SH) - 1) >> SH;        // buckets (<=512 for n<=131072)
    int NC = (EE + CHA - 1) / CHA;             // chunks
    int M  = NB * NC;
    int NBLK = (M + SCB - 1) / SCB;            // scan blocks (<=32 here)

    char* w = (char*)d_ws;
    size_t off = 0;
    auto take = [&](size_t elems) { void* p = w + off; off += ((elems * 4 + 255) & ~(size_t)255); return p; };
    int* bmat      = (int*)take((size_t)M);
    int* bsums     = (int*)take(256);
    uint4* bfg     = (uint4*)take(8192);       // 32 KB packed W1 fragments
    unsigned* recs = (unsigned*)take((size_t)EE);
    int* row_off   = (int*)take((size_t)n + 1);
    int* csr       = (int*)take((size_t)EE);
    float* as1     = (float*)take((size_t)n * 4);
    float* ad1     = (float*)take((size_t)n * 4);
    unsigned short* h1h = (unsigned short*)take((size_t)n * 64);  // n*128 fp16
    unsigned short* h2h = (unsigned short*)take((size_t)n * 16);  // n*32 fp16
    float* as2     = (float*)take((size_t)n);
    float* ad2     = (float*)take((size_t)n);

    // pre-pass: W1 -> packed MFMA B fragments (once)
    k_prepW<<<8, 256, 0, stream>>>(W1, bfg);

    // fused: bhist (blocks 0..NC-1) + MFMA layer-1 GEMM (rest)
    int ntile = (n + 63) / 64;
    k_gemm1m<<<NC + ntile, 256, 0, stream>>>(x, bfg, as1w, ad1w, ei, bmat,
                                             h1h, as1, ad1, n, E_, NB, NC);

    // CSR build (bucketed counting sort; scanB folded into consumers)
    k_scanA   <<<NBLK, 256, 0, stream>>>(bmat, bsums, M);
    k_bscatter<<<NC, 256, 0, stream>>>(ei, bmat, bsums, recs, E_, n, NB, NC, NBLK);
    k_bfill   <<<NB, 256, 0, stream>>>(recs, bmat, bsums, row_off, csr, n, NB, NC, EE, NBLK);

    // fused layer-1 GAT + layer-2 GEMM (z stays on-chip)
    int gG = (n + 15) / 16;
    k_gat1<<<gG, 256, 0, stream>>>(row_off, csr, as1, ad1, h1h, b1,
                                   W2, as2w, ad2w, h2h, as2, ad2, n);

    // layer-2 GAT + log_softmax
    int gG2 = (n + 63) / 64;
    k_gat2<<<gG2, 256, 0, stream>>>(row_off, csr, as2, ad2, h2h, b2, out, n);
}

// Round 14
// 284.620 us; speedup vs baseline: 1.0081x; 1.0081x over previous
//
#include <hip/hip_runtime.h>
#include <hip/hip_fp16.h>
#include <math.h>

#define IN_C   128
#define HEADS  4
#define F1     128   // HEADS*HID
#define OUT_C  32
#define NEG    0.2f
#define SH     8     // bucket = dst >> SH (256 dsts per bucket); needs n <= 2^17
#define CHA    8192  // edges per chunk in CSR pass A
#define SCB    4096  // elements per scan block (256 thr x 16)

// ---- fp16 helpers (RNE) ----
__device__ __forceinline__ unsigned short f2h(float f) {
    return __half_as_ushort(__float2half_rn(f));
}
__device__ __forceinline__ float h2f(unsigned short u) {
    return __half2float(__ushort_as_half(u));
}
__device__ __forceinline__ float hlo(unsigned u) { return h2f((unsigned short)(u & 0xffffu)); }
__device__ __forceinline__ float hhi(unsigned u) { return h2f((unsigned short)(u >> 16)); }
__device__ __forceinline__ unsigned pk2(float a, float b) {
    return (unsigned)f2h(a) | ((unsigned)f2h(b) << 16);
}
typedef _Float16 h2v  __attribute__((ext_vector_type(2)));
typedef _Float16 f16x4v __attribute__((ext_vector_type(4)));
typedef _Float16 f16x8v __attribute__((ext_vector_type(8)));
typedef float    f32x4v __attribute__((ext_vector_type(4)));
__device__ __forceinline__ h2v u2h2(unsigned u) {
    h2v r; __builtin_memcpy(&r, &u, 4); return r;
}
__device__ __forceinline__ float dot2(unsigned a, unsigned b, float c) {
    return __builtin_amdgcn_fdot2(u2h2(a), u2h2(b), c, false);
}
// v_perm: D = (A.lo16, B.lo16) with perm(B, A, PERM_LO)  [A -> low half]
#define PERM_LO 0x05040100u
#define PERM_HI 0x07060302u
__device__ __forceinline__ float pdot(unsigned b, unsigned a, unsigned sel, h2v pv, float c) {
    return __builtin_amdgcn_fdot2(u2h2(__builtin_amdgcn_perm(b, a, sel)), pv, c, false);
}

// ============ pre-pass: W1 -> packed B fragments (once, 32 KB global) ========
__global__ __launch_bounds__(256) void k_prepW(
    const float* __restrict__ W, uint4* __restrict__ bfg)
{
    int i = blockIdx.x * 256 + threadIdx.x;   // frag-lane id, 2048 total
    if (i >= 2048) return;
    int f = i >> 6, l = i & 63;
    int s = f >> 3, ct = f & 7;
    int col = ct * 16 + (l & 15);
    int k0 = s * 32 + (l >> 4) * 8;
    const float* wp = &W[(size_t)k0 * 128 + col];
    unsigned short u0 = f2h(wp[0]);
    unsigned short u1 = f2h(wp[128]);
    unsigned short u2 = f2h(wp[256]);
    unsigned short u3 = f2h(wp[384]);
    unsigned short u4 = f2h(wp[512]);
    unsigned short u5 = f2h(wp[640]);
    unsigned short u6 = f2h(wp[768]);
    unsigned short u7 = f2h(wp[896]);
    uint4 p;
    p.x = (unsigned)u0 | ((unsigned)u1 << 16);
    p.y = (unsigned)u2 | ((unsigned)u3 << 16);
    p.z = (unsigned)u4 | ((unsigned)u5 << 16);
    p.w = (unsigned)u6 | ((unsigned)u7 << 16);
    bfg[i] = p;
}

// ============ fused: CSR pass A1 (bucket histogram) ∥ layer-1 MFMA GEMM ======
// blockIdx < NC  -> bhist role; else -> gemm role (h1 = x@W1 via MFMA).
// h1h store now COALESCED: 4 passes, wave writes 1 KB contiguous per instr
// (lane l -> row w*16+p*4+(l>>4), logical slot l&15; LDS read at physical
// slot (l&15)^(row&7) — inverse of the store swizzle, bit-identical data).
__global__ __launch_bounds__(256) void k_gemm1m(
    const float* __restrict__ x, const uint4* __restrict__ bfg,
    const float* __restrict__ as_w, const float* __restrict__ ad_w,
    const int* __restrict__ ei, int* __restrict__ bmat,
    unsigned short* __restrict__ h1h, float* __restrict__ as1,
    float* __restrict__ ad1, int n, int E_, int NB, int NC)
{
    __shared__ char lds[49152];
    int t = threadIdx.x;

    if ((int)blockIdx.x < NC) {          // ---- bhist role ----
        int* h = (int*)lds;
        int c = blockIdx.x;
        for (int i = t; i < NB; i += 256) h[i] = 0;
        __syncthreads();
        int e0 = c * CHA, e1 = min(e0 + CHA, E_ + n);
        for (int e = e0 + t; e < e1; e += 256) {
            int d = (e < E_) ? ei[E_ + e] : e - E_;
            atomicAdd(&h[d >> SH], 1);
        }
        __syncthreads();
        for (int i = t; i < NB; i += 256) bmat[i * NC + c] = h[i];
        return;
    }

    // ---- gemm role ----
    char* xhB = lds;               // 16 KB: x/h tile [64 rows][128 f16], XOR-swizzled
    char* bfB = lds + 16384;       // 32 KB: Bf[32 frags][64 lanes][16 B]
    int n0 = ((int)blockIdx.x - NC) * 64;

    // stage x tile fp16 (coalesced float4 reads, vector 8B LDS stores)
    for (int i = t; i < 64 * 32; i += 256) {
        int node = i >> 5, k4 = (i & 31) * 4;
        int nn = n0 + node;
        float4 v = (nn < n) ? *(const float4*)&x[(size_t)nn * 128 + k4]
                            : make_float4(0.f, 0.f, 0.f, 0.f);
        f16x4v hv = { (_Float16)v.x, (_Float16)v.y, (_Float16)v.z, (_Float16)v.w };
        *(f16x4v*)(xhB + node * 256 + ((2 * k4) ^ ((node & 7) << 4))) = hv;
    }
    // stage B fragments: coalesced linear copy of precomputed bfg (32 KB)
    for (int i = t; i < 2048; i += 256)
        *(uint4*)(bfB + (size_t)i * 16) = bfg[i];
    __syncthreads();

    int w = t >> 6, l = t & 63, g = l >> 4, cl = l & 15;
    int arow = w * 16 + cl;            // A row (local) for this lane
    f32x4v acc[8] = {};
    #pragma unroll
    for (int s = 0; s < 4; ++s) {
        int k2 = 2 * (s * 32 + g * 8);
        f16x8v a = *(f16x8v*)(xhB + arow * 256 + (k2 ^ ((arow & 7) << 4)));
        #pragma unroll
        for (int ct = 0; ct < 8; ++ct) {
            f16x8v b = *(f16x8v*)(bfB + ((s * 8 + ct) * 64 + l) * 16);
            acc[ct] = __builtin_amdgcn_mfma_f32_16x16x32_f16(a, b, acc[ct], 0, 0, 0);
        }
    }

    // fused attention partials (D: col=lane&15, row=g*4+r) — R8-verified
    #pragma unroll
    for (int h = 0; h < 4; ++h) {
        float asw0 = as_w[h * 32 + cl],      adw0 = ad_w[h * 32 + cl];
        float asw1 = as_w[h * 32 + 16 + cl], adw1 = ad_w[h * 32 + 16 + cl];
        float ps[4], pd[4];
        #pragma unroll
        for (int r = 0; r < 4; ++r) {
            ps[r] = acc[2 * h][r] * asw0 + acc[2 * h + 1][r] * asw1;
            pd[r] = acc[2 * h][r] * adw0 + acc[2 * h + 1][r] * adw1;
        }
        #pragma unroll
        for (int o = 1; o < 16; o <<= 1) {
            #pragma unroll
            for (int r = 0; r < 4; ++r) {
                ps[r] += __shfl_xor(ps[r], o);
                pd[r] += __shfl_xor(pd[r], o);
            }
        }
        if (cl == h) {
            #pragma unroll
            for (int r = 0; r < 4; ++r) {
                int node = n0 + w * 16 + g * 4 + r;
                if (node < n) {
                    as1[(size_t)node * 4 + h] = ps[r];
                    ad1[(size_t)node * 4 + h] = pd[r];
                }
            }
        }
    }

    // h1 -> LDS (swizzled, own-wave rows; x-tile fully consumed)
    #pragma unroll
    for (int tt = 0; tt < 8; ++tt) {
        int cc = tt * 16 + cl;
        #pragma unroll
        for (int r = 0; r < 4; ++r) {
            int rl = w * 16 + g * 4 + r;
            *(_Float16*)(xhB + rl * 256 + ((2 * cc) ^ ((rl & 7) << 4))) = (_Float16)acc[tt][r];
        }
    }
    __threadfence_block();
    // COALESCED global store: 4 passes x (wave = 4 rows x 16 slots = 1 KB contig)
    #pragma unroll
    for (int p = 0; p < 4; ++p) {
        int row = w * 16 + p * 4 + (l >> 4);
        int sl  = l & 15;
        int node2 = n0 + row;
        if (node2 < n) {
            uint4 val = *(uint4*)(xhB + row * 256 + ((16 * sl) ^ ((row & 7) << 4)));
            *(uint4*)&h1h[(size_t)node2 * 128 + 8 * sl] = val;
        }
    }
}

// ============ CSR pass A2: parallel exclusive scan of bmat ===================
__global__ __launch_bounds__(256) void k_scanA(
    int* __restrict__ bmat, int* __restrict__ bsums, int M)
{
    __shared__ int sm[256];
    int t = threadIdx.x;
    int base = blockIdx.x * SCB + t * 16;
    int v[16];
    int s = 0;
    #pragma unroll
    for (int j = 0; j < 16; ++j) {
        int i = base + j;
        v[j] = (i < M) ? bmat[i] : 0;
        s += v[j];
    }
    sm[t] = s;
    __syncthreads();
    for (int off = 1; off < 256; off <<= 1) {
        int a = (t >= off) ? sm[t - off] : 0;
        __syncthreads();
        sm[t] += a;
        __syncthreads();
    }
    int excl = sm[t] - s;
    #pragma unroll
    for (int j = 0; j < 16; ++j) {
        int i = base + j;
        if (i < M) bmat[i] = excl;
        excl += v[j];
    }
    if (t == 255) bsums[blockIdx.x] = sm[255];
}

// ============ CSR pass A3: scatter packed recs into (bucket,chunk) ranges =====
__global__ __launch_bounds__(256) void k_bscatter(
    const int* __restrict__ ei, const int* __restrict__ bmat,
    const int* __restrict__ bsums, unsigned* __restrict__ recs,
    int E_, int n, int NB, int NC, int NBLK)
{
    __shared__ int cur[512];
    __shared__ int pref[32];
    int t = threadIdx.x, c = blockIdx.x;
    if (t < 32) {                     // exclusive prefix of bsums (<=32 entries)
        int v0 = (t < NBLK) ? bsums[t] : 0;
        int v = v0;
        #pragma unroll
        for (int o = 1; o < 32; o <<= 1) {
            int u = __shfl_up(v, o);
            if (t >= o) v += u;
        }
        pref[t] = v - v0;
    }
    __syncthreads();
    for (int i = t; i < NB; i += 256) {
        int m = i * NC + c;
        cur[i] = bmat[m] + pref[m >> 12];
    }
    __syncthreads();
    int e0 = c * CHA, e1 = min(e0 + CHA, E_ + n);
    for (int e = e0 + t; e < e1; e += 256) {
        int s, d;
        if (e < E_) { s = ei[e]; d = ei[E_ + e]; } else { s = d = e - E_; }
        int b = d >> SH;
        int p = atomicAdd(&cur[b], 1);   // LDS atomic
        recs[p] = ((unsigned)(d & ((1 << SH) - 1)) << 17) | (unsigned)s;
    }
}

// ============ CSR pass B: per-bucket fine fill (one block owns one bucket) ====
__global__ __launch_bounds__(256) void k_bfill(
    const unsigned* __restrict__ recs, const int* __restrict__ bmat,
    const int* __restrict__ bsums, int* __restrict__ row_off,
    int* __restrict__ csr, int n, int NB, int NC, int EE, int NBLK)
{
    __shared__ int deg[256];
    __shared__ int cur[256];
    __shared__ int pref[32];
    int t = threadIdx.x, b = blockIdx.x;
    if (t < 32) {
        int v0 = (t < NBLK) ? bsums[t] : 0;
        int v = v0;
        #pragma unroll
        for (int o = 1; o < 32; o <<= 1) {
            int u = __shfl_up(v, o);
            if (t >= o) v += u;
        }
        pref[t] = v - v0;
    }
    deg[t] = 0;
    __syncthreads();
    int m0 = b * NC;
    int r0 = bmat[m0] + pref[m0 >> 12];
    int r1 = EE;
    if (b + 1 < NB) {
        int m1 = (b + 1) * NC;
        r1 = bmat[m1] + pref[m1 >> 12];
    }
    for (int i = r0 + t; i < r1; i += 256)
        atomicAdd(&deg[recs[i] >> 17], 1);
    __syncthreads();
    int v = deg[t];
    for (int off = 1; off < 256; off <<= 1) {
        int a = (t >= off) ? deg[t - off] : 0;
        __syncthreads();
        deg[t] += a;
        __syncthreads();
    }
    int excl = deg[t] - v;
    int dst = (b << SH) + t;
    if (dst < n) row_off[dst] = r0 + excl;
    cur[t] = excl;
    if (b == NB - 1 && t == 0) row_off[n] = EE;
    __syncthreads();
    for (int i = r0 + t; i < r1; i += 256) {
        unsigned rec = recs[i];
        int dl = rec >> 17;
        int p = atomicAdd(&cur[dl], 1);   // LDS atomic
        csr[r0 + p] = (int)(rec & 0x1FFFFu);
    }
}

// ====== fused layer-1 GAT + layer-2 GEMM: softmax/gather/ELU + h2=z@W2 =======
__global__ __launch_bounds__(256) void k_gat1(
    const int* __restrict__ row_off, const int* __restrict__ csr,
    const float* __restrict__ as1, const float* __restrict__ ad1,
    const unsigned short* __restrict__ h1h, const float* __restrict__ b1,
    const float* __restrict__ W2, const float* __restrict__ as2w,
    const float* __restrict__ ad2w, unsigned short* __restrict__ h2h,
    float* __restrict__ as2, float* __restrict__ ad2, int n)
{
    __shared__ int      s_src[16][36];     // 2.25 KB, byte offsets
    __shared__ unsigned s_pw[16][4][17];   // 4.25 KB, [node][head][pair-word]
    __shared__ unsigned W2s[64 * 32];      // 8 KB, [k2][col] packed pairs
    __shared__ unsigned zs[16][66];        // 4.1 KB, z rows packed (pad 66)
    int t = threadIdx.x;

    for (int i = t; i < 64 * 8; i += 256) {
        int k2 = i >> 3, c4 = (i & 7) * 4;
        float4 a = *(const float4*)&W2[(2 * k2) * 32 + c4];
        float4 b = *(const float4*)&W2[(2 * k2 + 1) * 32 + c4];
        uint4 p;
        p.x = pk2(a.x, b.x); p.y = pk2(a.y, b.y);
        p.z = pk2(a.z, b.z); p.w = pk2(a.w, b.w);
        *(uint4*)&W2s[k2 * 32 + c4] = p;
    }
    __syncthreads();

    int nb = t >> 4;                // node slot in block (0..15)
    int hl = t & 15;                // lane within node
    int node = blockIdx.x * 16 + nb;
    if (node < n) {
        int* ssrc = s_src[nb];
        unsigned (*spw)[17] = s_pw[nb];

        const char* h1b = (const char*)h1h;
        int chb  = hl << 4;         // byte offset of my 8 channels (8 * 2B)
        int head = hl >> 2;         // my head (channels hl*8 .. hl*8+7)

        float4 addv = *(const float4*)&ad1[(size_t)node * 4];
        int beg = row_off[node], end = row_off[node + 1];

        float sr0 = 0.f, sr1 = 0.f, sr2 = 0.f, sr3 = 0.f;
        float acc0 = 0.f, acc1 = 0.f, acc2 = 0.f, acc3 = 0.f;
        float acc4 = 0.f, acc5 = 0.f, acc6 = 0.f, acc7 = 0.f;

        for (int c = beg; c < end; c += 32) {
            int cnt = min(32, end - c);
            int e0 = hl << 1;       // this lane's 2 edges
            float ls0 = 0.f, ls1 = 0.f, ls2 = 0.f, ls3 = 0.f;
            if (e0 < cnt) {
                int sA = csr[c + e0];
                ssrc[e0] = sA << 8;
                float4 avA = *(const float4*)(as1 + ((unsigned)sA << 2));
                float v;
                unsigned short qa0, qa1, qa2, qa3;
                unsigned short qb0 = 0, qb1 = 0, qb2 = 0, qb3 = 0;
                v = avA.x + addv.x; v = v > 0.f ? v : NEG * v; qa0 = f2h(__expf(fminf(v, 10.f)));
                v = avA.y + addv.y; v = v > 0.f ? v : NEG * v; qa1 = f2h(__expf(fminf(v, 10.f)));
                v = avA.z + addv.z; v = v > 0.f ? v : NEG * v; qa2 = f2h(__expf(fminf(v, 10.f)));
                v = avA.w + addv.w; v = v > 0.f ? v : NEG * v; qa3 = f2h(__expf(fminf(v, 10.f)));
                if (e0 + 1 < cnt) {
                    int sB = csr[c + e0 + 1];
                    ssrc[e0 + 1] = sB << 8;
                    float4 avB = *(const float4*)(as1 + ((unsigned)sB << 2));
                    v = avB.x + addv.x; v = v > 0.f ? v : NEG * v; qb0 = f2h(__expf(fminf(v, 10.f)));
                    v = avB.y + addv.y; v = v > 0.f ? v : NEG * v; qb1 = f2h(__expf(fminf(v, 10.f)));
                    v = avB.z + addv.z; v = v > 0.f ? v : NEG * v; qb2 = f2h(__expf(fminf(v, 10.f)));
                    v = avB.w + addv.w; v = v > 0.f ? v : NEG * v; qb3 = f2h(__expf(fminf(v, 10.f)));
                }
                spw[0][hl] = (unsigned)qa0 | ((unsigned)qb0 << 16);
                spw[1][hl] = (unsigned)qa1 | ((unsigned)qb1 << 16);
                spw[2][hl] = (unsigned)qa2 | ((unsigned)qb2 << 16);
                spw[3][hl] = (unsigned)qa3 | ((unsigned)qb3 << 16);
                ls0 = h2f(qa0) + h2f(qb0);
                ls1 = h2f(qa1) + h2f(qb1);
                ls2 = h2f(qa2) + h2f(qb2);
                ls3 = h2f(qa3) + h2f(qb3);
            }
            #pragma unroll
            for (int o = 8; o; o >>= 1) {
                ls0 += __shfl_xor(ls0, o);
                ls1 += __shfl_xor(ls1, o);
                ls2 += __shfl_xor(ls2, o);
                ls3 += __shfl_xor(ls3, o);
            }
            sr0 += ls0; sr1 += ls1; sr2 += ls2; sr3 += ls3;
            __threadfence_block();

            #define MAC8(A, B, pw) {                                          \
                h2v pv = u2h2(pw);                                            \
                acc0 = pdot(B.x, A.x, PERM_LO, pv, acc0);                     \
                acc1 = pdot(B.x, A.x, PERM_HI, pv, acc1);                     \
                acc2 = pdot(B.y, A.y, PERM_LO, pv, acc2);                     \
                acc3 = pdot(B.y, A.y, PERM_HI, pv, acc3);                     \
                acc4 = pdot(B.z, A.z, PERM_LO, pv, acc4);                     \
                acc5 = pdot(B.z, A.z, PERM_HI, pv, acc5);                     \
                acc6 = pdot(B.w, A.w, PERM_LO, pv, acc6);                     \
                acc7 = pdot(B.w, A.w, PERM_HI, pv, acc7);                     \
            }
            int j = 0;
            for (; j + 8 <= cnt; j += 8) {
                int2 o0 = *(const int2*)&ssrc[j];
                int2 o1 = *(const int2*)&ssrc[j + 2];
                int2 o2 = *(const int2*)&ssrc[j + 4];
                int2 o3 = *(const int2*)&ssrc[j + 6];
                int w0 = j >> 1;
                unsigned pw0 = spw[head][w0];
                unsigned pw1 = spw[head][w0 + 1];
                unsigned pw2 = spw[head][w0 + 2];
                unsigned pw3 = spw[head][w0 + 3];
                uint4 A0 = *(const uint4*)(h1b + (unsigned)(o0.x + chb));
                uint4 B0 = *(const uint4*)(h1b + (unsigned)(o0.y + chb));
                uint4 A1 = *(const uint4*)(h1b + (unsigned)(o1.x + chb));
                uint4 B1 = *(const uint4*)(h1b + (unsigned)(o1.y + chb));
                uint4 A2 = *(const uint4*)(h1b + (unsigned)(o2.x + chb));
                uint4 B2 = *(const uint4*)(h1b + (unsigned)(o2.y + chb));
                uint4 A3 = *(const uint4*)(h1b + (unsigned)(o3.x + chb));
                uint4 B3 = *(const uint4*)(h1b + (unsigned)(o3.y + chb));
                MAC8(A0, B0, pw0);
                MAC8(A1, B1, pw1);
                MAC8(A2, B2, pw2);
                MAC8(A3, B3, pw3);
            }
            for (; j + 2 <= cnt; j += 2) {
                int2 oo = *(const int2*)&ssrc[j];
                unsigned pw = spw[head][j >> 1];
                uint4 A = *(const uint4*)(h1b + (unsigned)(oo.x + chb));
                uint4 B = *(const uint4*)(h1b + (unsigned)(oo.y + chb));
                MAC8(A, B, pw);
            }
            if (j < cnt) {
                int o0 = ssrc[j];
                float p = hlo(spw[head][j >> 1]);
                uint4 A = *(const uint4*)(h1b + (unsigned)(o0 + chb));
                acc0 = fmaf(p, hlo(A.x), acc0);
                acc1 = fmaf(p, hhi(A.x), acc1);
                acc2 = fmaf(p, hlo(A.y), acc2);
                acc3 = fmaf(p, hhi(A.y), acc3);
                acc4 = fmaf(p, hlo(A.z), acc4);
                acc5 = fmaf(p, hhi(A.z), acc5);
                acc6 = fmaf(p, hlo(A.w), acc6);
                acc7 = fmaf(p, hhi(A.w), acc7);
            }
            #undef MAC8
        }
        float srh = head == 0 ? sr0 : head == 1 ? sr1 : head == 2 ? sr2 : sr3;
        float inv = 1.0f / srh;
        float4 bb0 = *(const float4*)&b1[hl * 8];
        float4 bb1 = *(const float4*)&b1[hl * 8 + 4];
        float v0 = acc0 * inv + bb0.x;
        float v1 = acc1 * inv + bb0.y;
        float v2 = acc2 * inv + bb0.z;
        float v3 = acc3 * inv + bb0.w;
        float v4 = acc4 * inv + bb1.x;
        float v5 = acc5 * inv + bb1.y;
        float v6 = acc6 * inv + bb1.z;
        float v7 = acc7 * inv + bb1.w;
        v0 = v0 > 0.f ? v0 : (__expf(v0) - 1.f);
        v1 = v1 > 0.f ? v1 : (__expf(v1) - 1.f);
        v2 = v2 > 0.f ? v2 : (__expf(v2) - 1.f);
        v3 = v3 > 0.f ? v3 : (__expf(v3) - 1.f);
        v4 = v4 > 0.f ? v4 : (__expf(v4) - 1.f);
        v5 = v5 > 0.f ? v5 : (__expf(v5) - 1.f);
        v6 = v6 > 0.f ? v6 : (__expf(v6) - 1.f);
        v7 = v7 > 0.f ? v7 : (__expf(v7) - 1.f);

        // ---- fused layer-2 GEMM epilogue: h2 = z @ W2 (z never hits HBM) ----
        unsigned* zrow = zs[nb];
        zrow[hl * 4 + 0] = pk2(v0, v1);
        zrow[hl * 4 + 1] = pk2(v2, v3);
        zrow[hl * 4 + 2] = pk2(v4, v5);
        zrow[hl * 4 + 3] = pk2(v6, v7);
        __threadfence_block();
        int c0 = hl * 2;            // my 2 output columns
        float a0 = 0.f, a1 = 0.f;
        #pragma unroll 8
        for (int k2 = 0; k2 < 64; ++k2) {
            unsigned zp = zrow[k2];
            uint2 wp = *(const uint2*)&W2s[k2 * 32 + c0];
            a0 = dot2(zp, wp.x, a0);
            a1 = dot2(zp, wp.y, a1);
        }
        *(unsigned*)&h2h[(size_t)node * 32 + c0] = pk2(a0, a1);
        float2 asw = *(const float2*)&as2w[c0];
        float2 adw = *(const float2*)&ad2w[c0];
        float sa = a0 * asw.x + a1 * asw.y;
        float sd = a0 * adw.x + a1 * adw.y;
        #pragma unroll
        for (int o = 8; o; o >>= 1) {
            sa += __shfl_xor(sa, o);
            sd += __shfl_xor(sd, o);
        }
        if (hl == 0) { as2[node] = sa; ad2[node] = sd; }
    }
}

// ============ fused layer-2 GAT + log_softmax: 4 lanes/node, 64 nodes/block ===
__global__ __launch_bounds__(256) void k_gat2(
    const int* __restrict__ row_off, const int* __restrict__ csr,
    const float* __restrict__ as2, const float* __restrict__ ad2,
    const unsigned short* __restrict__ h2h, const float* __restrict__ b2,
    float* __restrict__ y, int n)
{
    int nb = threadIdx.x >> 2;      // node slot in block (0..63)
    int hl = threadIdx.x & 3;       // lane within node
    int node = blockIdx.x * 64 + nb;
    if (node >= n) return;
    __shared__ int            s_src[64][34];   // 8.5 KB, row BYTE offsets (src<<6)
    __shared__ unsigned short s_p16[64][34];   // 4.25 KB fp16 p
    int* ssrc = s_src[nb];
    unsigned short* sp16 = s_p16[nb];

    const char* h2b = (const char*)h2h;
    int chb = hl << 4;              // byte offset of my 8 channels (8 * 2B)

    float addv = ad2[node];
    int beg = row_off[node], end = row_off[node + 1];
    float sr = 0.f;
    float acc0 = 0.f, acc1 = 0.f, acc2 = 0.f, acc3 = 0.f;
    float acc4 = 0.f, acc5 = 0.f, acc6 = 0.f, acc7 = 0.f;

    for (int c = beg; c < end; c += 32) {
        int cnt = min(32, end - c);
        int e0 = hl << 3;           // 8 edges per lane
        float ls = 0.f;
        #pragma unroll
        for (int k = 0; k < 8; k += 2) {
            int e = e0 + k;
            if (e < cnt) {
                unsigned short qa, qb = 0;
                int sA = csr[c + e];
                ssrc[e] = sA << 6;  // byte offset of fp16 row (32 ch * 2B)
                float v = as2[(unsigned)sA] + addv;
                v = v > 0.f ? v : NEG * v;
                qa = f2h(__expf(fminf(v, 10.f)));
                if (e + 1 < cnt) {
                    int sB = csr[c + e + 1];
                    ssrc[e + 1] = sB << 6;
                    float w2 = as2[(unsigned)sB] + addv;
                    w2 = w2 > 0.f ? w2 : NEG * w2;
                    qb = f2h(__expf(fminf(w2, 10.f)));
                }
                *(unsigned*)&sp16[e] = (unsigned)qa | ((unsigned)qb << 16);
                ls += h2f(qa) + h2f(qb);
            }
        }
        ls += __shfl_xor(ls, 1);
        ls += __shfl_xor(ls, 2);
        sr += ls;
        __threadfence_block();

        #define PAIR2(j) {                                                    \
            int2 oo = *(const int2*)&ssrc[j];                                 \
            unsigned pp = *(const unsigned*)&sp16[j];                         \
            uint4 A = *(const uint4*)(h2b + (unsigned)(oo.x + chb));          \
            uint4 B = *(const uint4*)(h2b + (unsigned)(oo.y + chb));          \
            h2v pv = u2h2(pp);                                                \
            acc0 = pdot(B.x, A.x, PERM_LO, pv, acc0);                         \
            acc1 = pdot(B.x, A.x, PERM_HI, pv, acc1);                         \
            acc2 = pdot(B.y, A.y, PERM_LO, pv, acc2);                         \
            acc3 = pdot(B.y, A.y, PERM_HI, pv, acc3);                         \
            acc4 = pdot(B.z, A.z, PERM_LO, pv, acc4);                         \
            acc5 = pdot(B.z, A.z, PERM_HI, pv, acc5);                         \
            acc6 = pdot(B.w, A.w, PERM_LO, pv, acc6);                         \
            acc7 = pdot(B.w, A.w, PERM_HI, pv, acc7);                         \
        }
        int jj = 0;
        for (; jj + 4 <= cnt; jj += 4) {
            PAIR2(jj);
            PAIR2(jj + 2);
        }
        if (jj + 2 <= cnt) {
            PAIR2(jj);
            jj += 2;
        }
        if (jj < cnt) {
            int o0 = ssrc[jj];
            float p = h2f(sp16[jj]);
            uint4 A = *(const uint4*)(h2b + (unsigned)(o0 + chb));
            acc0 = fmaf(p, hlo(A.x), acc0);
            acc1 = fmaf(p, hhi(A.x), acc1);
            acc2 = fmaf(p, hlo(A.y), acc2);
            acc3 = fmaf(p, hhi(A.y), acc3);
            acc4 = fmaf(p, hlo(A.z), acc4);
            acc5 = fmaf(p, hhi(A.z), acc5);
            acc6 = fmaf(p, hlo(A.w), acc6);
            acc7 = fmaf(p, hhi(A.w), acc7);
        }
        #undef PAIR2
    }
    float inv = 1.0f / sr;
    float4 bb0 = *(const float4*)&b2[hl * 8];
    float4 bb1 = *(const float4*)&b2[hl * 8 + 4];
    float v0 = acc0 * inv + bb0.x;
    float v1 = acc1 * inv + bb0.y;
    float v2 = acc2 * inv + bb0.z;
    float v3 = acc3 * inv + bb0.w;
    float v4 = acc4 * inv + bb1.x;
    float v5 = acc5 * inv + bb1.y;
    float v6 = acc6 * inv + bb1.z;
    float v7 = acc7 * inv + bb1.w;
    float m = fmaxf(fmaxf(fmaxf(v0, v1), fmaxf(v2, v3)),
                    fmaxf(fmaxf(v4, v5), fmaxf(v6, v7)));
    m = fmaxf(m, __shfl_xor(m, 1));
    m = fmaxf(m, __shfl_xor(m, 2));
    float ss = __expf(v0 - m) + __expf(v1 - m) + __expf(v2 - m) + __expf(v3 - m)
             + __expf(v4 - m) + __expf(v5 - m) + __expf(v6 - m) + __expf(v7 - m);
    ss += __shfl_xor(ss, 1);
    ss += __shfl_xor(ss, 2);
    float lg = m + logf(ss);
    float* yr = &y[(size_t)node * OUT_C + hl * 8];
    *(float4*)yr       = make_float4(v0 - lg, v1 - lg, v2 - lg, v3 - lg);
    *(float4*)(yr + 4) = make_float4(v4 - lg, v5 - lg, v6 - lg, v7 - lg);
}

extern "C" void kernel_launch(void* const* d_in, const int* in_sizes, int n_in,
                              void* d_out, int out_size, void* d_ws, size_t ws_size,
                              hipStream_t stream) {
    const float* x    = (const float*)d_in[0];
    const int*   ei   = (const int*)d_in[1];
    const float* W1   = (const float*)d_in[2];
    const float* as1w = (const float*)d_in[3];
    const float* ad1w = (const float*)d_in[4];
    const float* b1   = (const float*)d_in[5];
    const float* W2   = (const float*)d_in[6];
    const float* as2w = (const float*)d_in[7];
    const float* ad2w = (const float*)d_in[8];
    const float* b2   = (const float*)d_in[9];
    float* out = (float*)d_out;

    int n  = in_sizes[0] / IN_C;
    int E_ = in_sizes[1] / 2;
    int EE = E_ + n;

    int NB = (n + (1 << SH) - 1) >> SH;        // buckets (<=512 for n<=131072)
    int NC = (EE + CHA - 1) / CHA;             // chunks
    int M  = NB * NC;
    int NBLK = (M + SCB - 1) / SCB;            // scan blocks (<=32 here)

    char* w = (char*)d_ws;
    size_t off = 0;
    auto take = [&](size_t elems) { void* p = w + off; off += ((elems * 4 + 255) & ~(size_t)255); return p; };
    int* bmat      = (int*)take((size_t)M);
    int* bsums     = (int*)take(256);
    uint4* bfg     = (uint4*)take(8192);       // 32 KB packed W1 fragments
    unsigned* recs = (unsigned*)take((size_t)EE);
    int* row_off   = (int*)take((size_t)n + 1);
    int* csr       = (int*)take((size_t)EE);
    float* as1     = (float*)take((size_t)n * 4);
    float* ad1     = (float*)take((size_t)n * 4);
    unsigned short* h1h = (unsigned short*)take((size_t)n * 64);  // n*128 fp16
    unsigned short* h2h = (unsigned short*)take((size_t)n * 16);  // n*32 fp16
    float* as2     = (float*)take((size_t)n);
    float* ad2     = (float*)take((size_t)n);

    // pre-pass: W1 -> packed MFMA B fragments (once)
    k_prepW<<<8, 256, 0, stream>>>(W1, bfg);

    // fused: bhist (blocks 0..NC-1) + MFMA layer-1 GEMM (rest)
    int ntile = (n + 63) / 64;
    k_gemm1m<<<NC + ntile, 256, 0, stream>>>(x, bfg, as1w, ad1w, ei, bmat,
                                             h1h, as1, ad1, n, E_, NB, NC);

    // CSR build (bucketed counting sort; scanB folded into consumers)
    k_scanA   <<<NBLK, 256, 0, stream>>>(bmat, bsums, M);
    k_bscatter<<<NC, 256, 0, stream>>>(ei, bmat, bsums, recs, E_, n, NB, NC, NBLK);
    k_bfill   <<<NB, 256, 0, stream>>>(recs, bmat, bsums, row_off, csr, n, NB, NC, EE, NBLK);

    // fused layer-1 GAT + layer-2 GEMM (z stays on-chip)
    int gG = (n + 15) / 16;
    k_gat1<<<gG, 256, 0, stream>>>(row_off, csr, as1, ad1, h1h, b1,
                                   W2, as2w, ad2w, h2h, as2, ad2, n);

    // layer-2 GAT + log_softmax
    int gG2 = (n + 63) / 64;
    k_gat2<<<gG2, 256, 0, stream>>>(row_off, csr, as2, ad2, h2h, b2, out, n);
}

// Round 15
// 280.384 us; speedup vs baseline: 1.0234x; 1.0151x over previous
//
#include <hip/hip_runtime.h>
#include <hip/hip_fp16.h>
#include <math.h>

#define IN_C   128
#define HEADS  4
#define F1     128   // HEADS*HID
#define OUT_C  32
#define NEG    0.2f
#define SH     8     // bucket = dst >> SH (256 dsts per bucket); needs n <= 2^17
#define CHA    8192  // edges per chunk in CSR pass A
#define SCB    4096  // elements per scan block (256 thr x 16)

// ---- fp16 helpers (RNE) ----
__device__ __forceinline__ unsigned short f2h(float f) {
    return __half_as_ushort(__float2half_rn(f));
}
__device__ __forceinline__ float h2f(unsigned short u) {
    return __half2float(__ushort_as_half(u));
}
__device__ __forceinline__ float hlo(unsigned u) { return h2f((unsigned short)(u & 0xffffu)); }
__device__ __forceinline__ float hhi(unsigned u) { return h2f((unsigned short)(u >> 16)); }
__device__ __forceinline__ unsigned pk2(float a, float b) {
    return (unsigned)f2h(a) | ((unsigned)f2h(b) << 16);
}
typedef _Float16 h2v  __attribute__((ext_vector_type(2)));
typedef _Float16 f16x4v __attribute__((ext_vector_type(4)));
typedef _Float16 f16x8v __attribute__((ext_vector_type(8)));
typedef float    f32x4v __attribute__((ext_vector_type(4)));
__device__ __forceinline__ h2v u2h2(unsigned u) {
    h2v r; __builtin_memcpy(&r, &u, 4); return r;
}
__device__ __forceinline__ f16x8v u2h8(uint4 u) {
    f16x8v r; __builtin_memcpy(&r, &u, 16); return r;
}
__device__ __forceinline__ float dot2(unsigned a, unsigned b, float c) {
    return __builtin_amdgcn_fdot2(u2h2(a), u2h2(b), c, false);
}
// v_perm: D = (A.lo16, B.lo16) with perm(B, A, PERM_LO)  [A -> low half]
#define PERM_LO 0x05040100u
#define PERM_HI 0x07060302u
__device__ __forceinline__ float pdot(unsigned b, unsigned a, unsigned sel, h2v pv, float c) {
    return __builtin_amdgcn_fdot2(u2h2(__builtin_amdgcn_perm(b, a, sel)), pv, c, false);
}

// ============ pre-pass: W1 -> packed B fragments (once, 32 KB global) ========
__global__ __launch_bounds__(256) void k_prepW(
    const float* __restrict__ W, uint4* __restrict__ bfg)
{
    int i = blockIdx.x * 256 + threadIdx.x;   // frag-lane id, 2048 total
    if (i >= 2048) return;
    int f = i >> 6, l = i & 63;
    int s = f >> 3, ct = f & 7;
    int col = ct * 16 + (l & 15);
    int k0 = s * 32 + (l >> 4) * 8;
    const float* wp = &W[(size_t)k0 * 128 + col];
    unsigned short u0 = f2h(wp[0]);
    unsigned short u1 = f2h(wp[128]);
    unsigned short u2 = f2h(wp[256]);
    unsigned short u3 = f2h(wp[384]);
    unsigned short u4 = f2h(wp[512]);
    unsigned short u5 = f2h(wp[640]);
    unsigned short u6 = f2h(wp[768]);
    unsigned short u7 = f2h(wp[896]);
    uint4 p;
    p.x = (unsigned)u0 | ((unsigned)u1 << 16);
    p.y = (unsigned)u2 | ((unsigned)u3 << 16);
    p.z = (unsigned)u4 | ((unsigned)u5 << 16);
    p.w = (unsigned)u6 | ((unsigned)u7 << 16);
    bfg[i] = p;
}

// ============ fused: CSR pass A1 (bucket histogram) ∥ layer-1 MFMA GEMM ======
// blockIdx < NC  -> bhist role; else -> gemm role (h1 = x@W1 via MFMA).
// B fragments read DIRECTLY from global bfg in the MFMA loop (32 KB table,
// L2-hot, shared by all blocks; 1 KB/wave-instr coalesced). LDS = 16 KB only
// (x/h tile) -> occupancy cap rises from 3 to ~10 blocks/CU.
__global__ __launch_bounds__(256) void k_gemm1m(
    const float* __restrict__ x, const uint4* __restrict__ bfg,
    const float* __restrict__ as_w, const float* __restrict__ ad_w,
    const int* __restrict__ ei, int* __restrict__ bmat,
    unsigned short* __restrict__ h1h, float* __restrict__ as1,
    float* __restrict__ ad1, int n, int E_, int NB, int NC)
{
    __shared__ char lds[16384];
    int t = threadIdx.x;

    if ((int)blockIdx.x < NC) {          // ---- bhist role ----
        int* h = (int*)lds;
        int c = blockIdx.x;
        for (int i = t; i < NB; i += 256) h[i] = 0;
        __syncthreads();
        int e0 = c * CHA, e1 = min(e0 + CHA, E_ + n);
        for (int e = e0 + t; e < e1; e += 256) {
            int d = (e < E_) ? ei[E_ + e] : e - E_;
            atomicAdd(&h[d >> SH], 1);
        }
        __syncthreads();
        for (int i = t; i < NB; i += 256) bmat[i * NC + c] = h[i];
        return;
    }

    // ---- gemm role ----
    char* xhB = lds;               // 16 KB: x/h tile [64 rows][128 f16], XOR-swizzled
    int n0 = ((int)blockIdx.x - NC) * 64;

    // stage x tile fp16 (coalesced float4 reads, vector 8B LDS stores)
    for (int i = t; i < 64 * 32; i += 256) {
        int node = i >> 5, k4 = (i & 31) * 4;
        int nn = n0 + node;
        float4 v = (nn < n) ? *(const float4*)&x[(size_t)nn * 128 + k4]
                            : make_float4(0.f, 0.f, 0.f, 0.f);
        f16x4v hv = { (_Float16)v.x, (_Float16)v.y, (_Float16)v.z, (_Float16)v.w };
        *(f16x4v*)(xhB + node * 256 + ((2 * k4) ^ ((node & 7) << 4))) = hv;
    }
    __syncthreads();

    int w = t >> 6, l = t & 63, g = l >> 4, cl = l & 15;
    int arow = w * 16 + cl;            // A row (local) for this lane
    f32x4v acc[8] = {};
    #pragma unroll
    for (int s = 0; s < 4; ++s) {
        int k2 = 2 * (s * 32 + g * 8);
        f16x8v a = *(f16x8v*)(xhB + arow * 256 + (k2 ^ ((arow & 7) << 4)));
        #pragma unroll
        for (int ct = 0; ct < 8; ++ct) {
            f16x8v b = u2h8(bfg[(s * 8 + ct) * 64 + l]);   // L2-hit, 1 KB/wave
            acc[ct] = __builtin_amdgcn_mfma_f32_16x16x32_f16(a, b, acc[ct], 0, 0, 0);
        }
    }

    // fused attention partials (D: col=lane&15, row=g*4+r) — R8-verified
    #pragma unroll
    for (int h = 0; h < 4; ++h) {
        float asw0 = as_w[h * 32 + cl],      adw0 = ad_w[h * 32 + cl];
        float asw1 = as_w[h * 32 + 16 + cl], adw1 = ad_w[h * 32 + 16 + cl];
        float ps[4], pd[4];
        #pragma unroll
        for (int r = 0; r < 4; ++r) {
            ps[r] = acc[2 * h][r] * asw0 + acc[2 * h + 1][r] * asw1;
            pd[r] = acc[2 * h][r] * adw0 + acc[2 * h + 1][r] * adw1;
        }
        #pragma unroll
        for (int o = 1; o < 16; o <<= 1) {
            #pragma unroll
            for (int r = 0; r < 4; ++r) {
                ps[r] += __shfl_xor(ps[r], o);
                pd[r] += __shfl_xor(pd[r], o);
            }
        }
        if (cl == h) {
            #pragma unroll
            for (int r = 0; r < 4; ++r) {
                int node = n0 + w * 16 + g * 4 + r;
                if (node < n) {
                    as1[(size_t)node * 4 + h] = ps[r];
                    ad1[(size_t)node * 4 + h] = pd[r];
                }
            }
        }
    }

    // h1 -> LDS (swizzled, own-wave rows; x-tile fully consumed)
    #pragma unroll
    for (int tt = 0; tt < 8; ++tt) {
        int cc = tt * 16 + cl;
        #pragma unroll
        for (int r = 0; r < 4; ++r) {
            int rl = w * 16 + g * 4 + r;
            *(_Float16*)(xhB + rl * 256 + ((2 * cc) ^ ((rl & 7) << 4))) = (_Float16)acc[tt][r];
        }
    }
    __threadfence_block();
    // COALESCED global store: 4 passes x (wave = 4 rows x 16 slots = 1 KB contig)
    #pragma unroll
    for (int p = 0; p < 4; ++p) {
        int row = w * 16 + p * 4 + (l >> 4);
        int sl  = l & 15;
        int node2 = n0 + row;
        if (node2 < n) {
            uint4 val = *(uint4*)(xhB + row * 256 + ((16 * sl) ^ ((row & 7) << 4)));
            *(uint4*)&h1h[(size_t)node2 * 128 + 8 * sl] = val;
        }
    }
}

// ============ CSR pass A2: parallel exclusive scan of bmat ===================
__global__ __launch_bounds__(256) void k_scanA(
    int* __restrict__ bmat, int* __restrict__ bsums, int M)
{
    __shared__ int sm[256];
    int t = threadIdx.x;
    int base = blockIdx.x * SCB + t * 16;
    int v[16];
    int s = 0;
    #pragma unroll
    for (int j = 0; j < 16; ++j) {
        int i = base + j;
        v[j] = (i < M) ? bmat[i] : 0;
        s += v[j];
    }
    sm[t] = s;
    __syncthreads();
    for (int off = 1; off < 256; off <<= 1) {
        int a = (t >= off) ? sm[t - off] : 0;
        __syncthreads();
        sm[t] += a;
        __syncthreads();
    }
    int excl = sm[t] - s;
    #pragma unroll
    for (int j = 0; j < 16; ++j) {
        int i = base + j;
        if (i < M) bmat[i] = excl;
        excl += v[j];
    }
    if (t == 255) bsums[blockIdx.x] = sm[255];
}

// ============ CSR pass A3: scatter packed recs into (bucket,chunk) ranges =====
__global__ __launch_bounds__(256) void k_bscatter(
    const int* __restrict__ ei, const int* __restrict__ bmat,
    const int* __restrict__ bsums, unsigned* __restrict__ recs,
    int E_, int n, int NB, int NC, int NBLK)
{
    __shared__ int cur[512];
    __shared__ int pref[32];
    int t = threadIdx.x, c = blockIdx.x;
    if (t < 32) {                     // exclusive prefix of bsums (<=32 entries)
        int v0 = (t < NBLK) ? bsums[t] : 0;
        int v = v0;
        #pragma unroll
        for (int o = 1; o < 32; o <<= 1) {
            int u = __shfl_up(v, o);
            if (t >= o) v += u;
        }
        pref[t] = v - v0;
    }
    __syncthreads();
    for (int i = t; i < NB; i += 256) {
        int m = i * NC + c;
        cur[i] = bmat[m] + pref[m >> 12];
    }
    __syncthreads();
    int e0 = c * CHA, e1 = min(e0 + CHA, E_ + n);
    for (int e = e0 + t; e < e1; e += 256) {
        int s, d;
        if (e < E_) { s = ei[e]; d = ei[E_ + e]; } else { s = d = e - E_; }
        int b = d >> SH;
        int p = atomicAdd(&cur[b], 1);   // LDS atomic
        recs[p] = ((unsigned)(d & ((1 << SH) - 1)) << 17) | (unsigned)s;
    }
}

// ============ CSR pass B: per-bucket fine fill (one block owns one bucket) ====
__global__ __launch_bounds__(256) void k_bfill(
    const unsigned* __restrict__ recs, const int* __restrict__ bmat,
    const int* __restrict__ bsums, int* __restrict__ row_off,
    int* __restrict__ csr, int n, int NB, int NC, int EE, int NBLK)
{
    __shared__ int deg[256];
    __shared__ int cur[256];
    __shared__ int pref[32];
    int t = threadIdx.x, b = blockIdx.x;
    if (t < 32) {
        int v0 = (t < NBLK) ? bsums[t] : 0;
        int v = v0;
        #pragma unroll
        for (int o = 1; o < 32; o <<= 1) {
            int u = __shfl_up(v, o);
            if (t >= o) v += u;
        }
        pref[t] = v - v0;
    }
    deg[t] = 0;
    __syncthreads();
    int m0 = b * NC;
    int r0 = bmat[m0] + pref[m0 >> 12];
    int r1 = EE;
    if (b + 1 < NB) {
        int m1 = (b + 1) * NC;
        r1 = bmat[m1] + pref[m1 >> 12];
    }
    for (int i = r0 + t; i < r1; i += 256)
        atomicAdd(&deg[recs[i] >> 17], 1);
    __syncthreads();
    int v = deg[t];
    for (int off = 1; off < 256; off <<= 1) {
        int a = (t >= off) ? deg[t - off] : 0;
        __syncthreads();
        deg[t] += a;
        __syncthreads();
    }
    int excl = deg[t] - v;
    int dst = (b << SH) + t;
    if (dst < n) row_off[dst] = r0 + excl;
    cur[t] = excl;
    if (b == NB - 1 && t == 0) row_off[n] = EE;
    __syncthreads();
    for (int i = r0 + t; i < r1; i += 256) {
        unsigned rec = recs[i];
        int dl = rec >> 17;
        int p = atomicAdd(&cur[dl], 1);   // LDS atomic
        csr[r0 + p] = (int)(rec & 0x1FFFFu);
    }
}

// ====== fused layer-1 GAT + layer-2 GEMM: softmax/gather/ELU + h2=z@W2 =======
__global__ __launch_bounds__(256) void k_gat1(
    const int* __restrict__ row_off, const int* __restrict__ csr,
    const float* __restrict__ as1, const float* __restrict__ ad1,
    const unsigned short* __restrict__ h1h, const float* __restrict__ b1,
    const float* __restrict__ W2, const float* __restrict__ as2w,
    const float* __restrict__ ad2w, unsigned short* __restrict__ h2h,
    float* __restrict__ as2, float* __restrict__ ad2, int n)
{
    __shared__ int      s_src[16][36];     // 2.25 KB, byte offsets
    __shared__ unsigned s_pw[16][4][17];   // 4.25 KB, [node][head][pair-word]
    __shared__ unsigned W2s[64 * 32];      // 8 KB, [k2][col] packed pairs
    __shared__ unsigned zs[16][66];        // 4.1 KB, z rows packed (pad 66)
    int t = threadIdx.x;

    for (int i = t; i < 64 * 8; i += 256) {
        int k2 = i >> 3, c4 = (i & 7) * 4;
        float4 a = *(const float4*)&W2[(2 * k2) * 32 + c4];
        float4 b = *(const float4*)&W2[(2 * k2 + 1) * 32 + c4];
        uint4 p;
        p.x = pk2(a.x, b.x); p.y = pk2(a.y, b.y);
        p.z = pk2(a.z, b.z); p.w = pk2(a.w, b.w);
        *(uint4*)&W2s[k2 * 32 + c4] = p;
    }
    __syncthreads();

    int nb = t >> 4;                // node slot in block (0..15)
    int hl = t & 15;                // lane within node
    int node = blockIdx.x * 16 + nb;
    if (node < n) {
        int* ssrc = s_src[nb];
        unsigned (*spw)[17] = s_pw[nb];

        const char* h1b = (const char*)h1h;
        int chb  = hl << 4;         // byte offset of my 8 channels (8 * 2B)
        int head = hl >> 2;         // my head (channels hl*8 .. hl*8+7)

        float4 addv = *(const float4*)&ad1[(size_t)node * 4];
        int beg = row_off[node], end = row_off[node + 1];

        float sr0 = 0.f, sr1 = 0.f, sr2 = 0.f, sr3 = 0.f;
        float acc0 = 0.f, acc1 = 0.f, acc2 = 0.f, acc3 = 0.f;
        float acc4 = 0.f, acc5 = 0.f, acc6 = 0.f, acc7 = 0.f;

        for (int c = beg; c < end; c += 32) {
            int cnt = min(32, end - c);
            int e0 = hl << 1;       // this lane's 2 edges
            float ls0 = 0.f, ls1 = 0.f, ls2 = 0.f, ls3 = 0.f;
            if (e0 < cnt) {
                int sA = csr[c + e0];
                ssrc[e0] = sA << 8;
                float4 avA = *(const float4*)(as1 + ((unsigned)sA << 2));
                float v;
                unsigned short qa0, qa1, qa2, qa3;
                unsigned short qb0 = 0, qb1 = 0, qb2 = 0, qb3 = 0;
                v = avA.x + addv.x; v = v > 0.f ? v : NEG * v; qa0 = f2h(__expf(fminf(v, 10.f)));
                v = avA.y + addv.y; v = v > 0.f ? v : NEG * v; qa1 = f2h(__expf(fminf(v, 10.f)));
                v = avA.z + addv.z; v = v > 0.f ? v : NEG * v; qa2 = f2h(__expf(fminf(v, 10.f)));
                v = avA.w + addv.w; v = v > 0.f ? v : NEG * v; qa3 = f2h(__expf(fminf(v, 10.f)));
                if (e0 + 1 < cnt) {
                    int sB = csr[c + e0 + 1];
                    ssrc[e0 + 1] = sB << 8;
                    float4 avB = *(const float4*)(as1 + ((unsigned)sB << 2));
                    v = avB.x + addv.x; v = v > 0.f ? v : NEG * v; qb0 = f2h(__expf(fminf(v, 10.f)));
                    v = avB.y + addv.y; v = v > 0.f ? v : NEG * v; qb1 = f2h(__expf(fminf(v, 10.f)));
                    v = avB.z + addv.z; v = v > 0.f ? v : NEG * v; qb2 = f2h(__expf(fminf(v, 10.f)));
                    v = avB.w + addv.w; v = v > 0.f ? v : NEG * v; qb3 = f2h(__expf(fminf(v, 10.f)));
                }
                spw[0][hl] = (unsigned)qa0 | ((unsigned)qb0 << 16);
                spw[1][hl] = (unsigned)qa1 | ((unsigned)qb1 << 16);
                spw[2][hl] = (unsigned)qa2 | ((unsigned)qb2 << 16);
                spw[3][hl] = (unsigned)qa3 | ((unsigned)qb3 << 16);
                ls0 = h2f(qa0) + h2f(qb0);
                ls1 = h2f(qa1) + h2f(qb1);
                ls2 = h2f(qa2) + h2f(qb2);
                ls3 = h2f(qa3) + h2f(qb3);
            }
            #pragma unroll
            for (int o = 8; o; o >>= 1) {
                ls0 += __shfl_xor(ls0, o);
                ls1 += __shfl_xor(ls1, o);
                ls2 += __shfl_xor(ls2, o);
                ls3 += __shfl_xor(ls3, o);
            }
            sr0 += ls0; sr1 += ls1; sr2 += ls2; sr3 += ls3;
            __threadfence_block();

            #define MAC8(A, B, pw) {                                          \
                h2v pv = u2h2(pw);                                            \
                acc0 = pdot(B.x, A.x, PERM_LO, pv, acc0);                     \
                acc1 = pdot(B.x, A.x, PERM_HI, pv, acc1);                     \
                acc2 = pdot(B.y, A.y, PERM_LO, pv, acc2);                     \
                acc3 = pdot(B.y, A.y, PERM_HI, pv, acc3);                     \
                acc4 = pdot(B.z, A.z, PERM_LO, pv, acc4);                     \
                acc5 = pdot(B.z, A.z, PERM_HI, pv, acc5);                     \
                acc6 = pdot(B.w, A.w, PERM_LO, pv, acc6);                     \
                acc7 = pdot(B.w, A.w, PERM_HI, pv, acc7);                     \
            }
            int j = 0;
            for (; j + 8 <= cnt; j += 8) {
                int2 o0 = *(const int2*)&ssrc[j];
                int2 o1 = *(const int2*)&ssrc[j + 2];
                int2 o2 = *(const int2*)&ssrc[j + 4];
                int2 o3 = *(const int2*)&ssrc[j + 6];
                int w0 = j >> 1;
                unsigned pw0 = spw[head][w0];
                unsigned pw1 = spw[head][w0 + 1];
                unsigned pw2 = spw[head][w0 + 2];
                unsigned pw3 = spw[head][w0 + 3];
                uint4 A0 = *(const uint4*)(h1b + (unsigned)(o0.x + chb));
                uint4 B0 = *(const uint4*)(h1b + (unsigned)(o0.y + chb));
                uint4 A1 = *(const uint4*)(h1b + (unsigned)(o1.x + chb));
                uint4 B1 = *(const uint4*)(h1b + (unsigned)(o1.y + chb));
                uint4 A2 = *(const uint4*)(h1b + (unsigned)(o2.x + chb));
                uint4 B2 = *(const uint4*)(h1b + (unsigned)(o2.y + chb));
                uint4 A3 = *(const uint4*)(h1b + (unsigned)(o3.x + chb));
                uint4 B3 = *(const uint4*)(h1b + (unsigned)(o3.y + chb));
                MAC8(A0, B0, pw0);
                MAC8(A1, B1, pw1);
                MAC8(A2, B2, pw2);
                MAC8(A3, B3, pw3);
            }
            for (; j + 2 <= cnt; j += 2) {
                int2 oo = *(const int2*)&ssrc[j];
                unsigned pw = spw[head][j >> 1];
                uint4 A = *(const uint4*)(h1b + (unsigned)(oo.x + chb));
                uint4 B = *(const uint4*)(h1b + (unsigned)(oo.y + chb));
                MAC8(A, B, pw);
            }
            if (j < cnt) {
                int o0 = ssrc[j];
                float p = hlo(spw[head][j >> 1]);
                uint4 A = *(const uint4*)(h1b + (unsigned)(o0 + chb));
                acc0 = fmaf(p, hlo(A.x), acc0);
                acc1 = fmaf(p, hhi(A.x), acc1);
                acc2 = fmaf(p, hlo(A.y), acc2);
                acc3 = fmaf(p, hhi(A.y), acc3);
                acc4 = fmaf(p, hlo(A.z), acc4);
                acc5 = fmaf(p, hhi(A.z), acc5);
                acc6 = fmaf(p, hlo(A.w), acc6);
                acc7 = fmaf(p, hhi(A.w), acc7);
            }
            #undef MAC8
        }
        float srh = head == 0 ? sr0 : head == 1 ? sr1 : head == 2 ? sr2 : sr3;
        float inv = 1.0f / srh;
        float4 bb0 = *(const float4*)&b1[hl * 8];
        float4 bb1 = *(const float4*)&b1[hl * 8 + 4];
        float v0 = acc0 * inv + bb0.x;
        float v1 = acc1 * inv + bb0.y;
        float v2 = acc2 * inv + bb0.z;
        float v3 = acc3 * inv + bb0.w;
        float v4 = acc4 * inv + bb1.x;
        float v5 = acc5 * inv + bb1.y;
        float v6 = acc6 * inv + bb1.z;
        float v7 = acc7 * inv + bb1.w;
        v0 = v0 > 0.f ? v0 : (__expf(v0) - 1.f);
        v1 = v1 > 0.f ? v1 : (__expf(v1) - 1.f);
        v2 = v2 > 0.f ? v2 : (__expf(v2) - 1.f);
        v3 = v3 > 0.f ? v3 : (__expf(v3) - 1.f);
        v4 = v4 > 0.f ? v4 : (__expf(v4) - 1.f);
        v5 = v5 > 0.f ? v5 : (__expf(v5) - 1.f);
        v6 = v6 > 0.f ? v6 : (__expf(v6) - 1.f);
        v7 = v7 > 0.f ? v7 : (__expf(v7) - 1.f);

        // ---- fused layer-2 GEMM epilogue: h2 = z @ W2 (z never hits HBM) ----
        unsigned* zrow = zs[nb];
        zrow[hl * 4 + 0] = pk2(v0, v1);
        zrow[hl * 4 + 1] = pk2(v2, v3);
        zrow[hl * 4 + 2] = pk2(v4, v5);
        zrow[hl * 4 + 3] = pk2(v6, v7);
        __threadfence_block();
        int c0 = hl * 2;            // my 2 output columns
        float a0 = 0.f, a1 = 0.f;
        #pragma unroll 8
        for (int k2 = 0; k2 < 64; ++k2) {
            unsigned zp = zrow[k2];
            uint2 wp = *(const uint2*)&W2s[k2 * 32 + c0];
            a0 = dot2(zp, wp.x, a0);
            a1 = dot2(zp, wp.y, a1);
        }
        *(unsigned*)&h2h[(size_t)node * 32 + c0] = pk2(a0, a1);
        float2 asw = *(const float2*)&as2w[c0];
        float2 adw = *(const float2*)&ad2w[c0];
        float sa = a0 * asw.x + a1 * asw.y;
        float sd = a0 * adw.x + a1 * adw.y;
        #pragma unroll
        for (int o = 8; o; o >>= 1) {
            sa += __shfl_xor(sa, o);
            sd += __shfl_xor(sd, o);
        }
        if (hl == 0) { as2[node] = sa; ad2[node] = sd; }
    }
}

// ============ fused layer-2 GAT + log_softmax: 4 lanes/node, 64 nodes/block ===
__global__ __launch_bounds__(256) void k_gat2(
    const int* __restrict__ row_off, const int* __restrict__ csr,
    const float* __restrict__ as2, const float* __restrict__ ad2,
    const unsigned short* __restrict__ h2h, const float* __restrict__ b2,
    float* __restrict__ y, int n)
{
    int nb = threadIdx.x >> 2;      // node slot in block (0..63)
    int hl = threadIdx.x & 3;       // lane within node
    int node = blockIdx.x * 64 + nb;
    if (node >= n) return;
    __shared__ int            s_src[64][34];   // 8.5 KB, row BYTE offsets (src<<6)
    __shared__ unsigned short s_p16[64][34];   // 4.25 KB fp16 p
    int* ssrc = s_src[nb];
    unsigned short* sp16 = s_p16[nb];

    const char* h2b = (const char*)h2h;
    int chb = hl << 4;              // byte offset of my 8 channels (8 * 2B)

    float addv = ad2[node];
    int beg = row_off[node], end = row_off[node + 1];
    float sr = 0.f;
    float acc0 = 0.f, acc1 = 0.f, acc2 = 0.f, acc3 = 0.f;
    float acc4 = 0.f, acc5 = 0.f, acc6 = 0.f, acc7 = 0.f;

    for (int c = beg; c < end; c += 32) {
        int cnt = min(32, end - c);
        int e0 = hl << 3;           // 8 edges per lane
        float ls = 0.f;
        #pragma unroll
        for (int k = 0; k < 8; k += 2) {
            int e = e0 + k;
            if (e < cnt) {
                unsigned short qa, qb = 0;
                int sA = csr[c + e];
                ssrc[e] = sA << 6;  // byte offset of fp16 row (32 ch * 2B)
                float v = as2[(unsigned)sA] + addv;
                v = v > 0.f ? v : NEG * v;
                qa = f2h(__expf(fminf(v, 10.f)));
                if (e + 1 < cnt) {
                    int sB = csr[c + e + 1];
                    ssrc[e + 1] = sB << 6;
                    float w2 = as2[(unsigned)sB] + addv;
                    w2 = w2 > 0.f ? w2 : NEG * w2;
                    qb = f2h(__expf(fminf(w2, 10.f)));
                }
                *(unsigned*)&sp16[e] = (unsigned)qa | ((unsigned)qb << 16);
                ls += h2f(qa) + h2f(qb);
            }
        }
        ls += __shfl_xor(ls, 1);
        ls += __shfl_xor(ls, 2);
        sr += ls;
        __threadfence_block();

        #define PAIR2(j) {                                                    \
            int2 oo = *(const int2*)&ssrc[j];                                 \
            unsigned pp = *(const unsigned*)&sp16[j];                         \
            uint4 A = *(const uint4*)(h2b + (unsigned)(oo.x + chb));          \
            uint4 B = *(const uint4*)(h2b + (unsigned)(oo.y + chb));          \
            h2v pv = u2h2(pp);                                                \
            acc0 = pdot(B.x, A.x, PERM_LO, pv, acc0);                         \
            acc1 = pdot(B.x, A.x, PERM_HI, pv, acc1);                         \
            acc2 = pdot(B.y, A.y, PERM_LO, pv, acc2);                         \
            acc3 = pdot(B.y, A.y, PERM_HI, pv, acc3);                         \
            acc4 = pdot(B.z, A.z, PERM_LO, pv, acc4);                         \
            acc5 = pdot(B.z, A.z, PERM_HI, pv, acc5);                         \
            acc6 = pdot(B.w, A.w, PERM_LO, pv, acc6);                         \
            acc7 = pdot(B.w, A.w, PERM_HI, pv, acc7);                         \
        }
        int jj = 0;
        for (; jj + 4 <= cnt; jj += 4) {
            PAIR2(jj);
            PAIR2(jj + 2);
        }
        if (jj + 2 <= cnt) {
            PAIR2(jj);
            jj += 2;
        }
        if (jj < cnt) {
            int o0 = ssrc[jj];
            float p = h2f(sp16[jj]);
            uint4 A = *(const uint4*)(h2b + (unsigned)(o0 + chb));
            acc0 = fmaf(p, hlo(A.x), acc0);
            acc1 = fmaf(p, hhi(A.x), acc1);
            acc2 = fmaf(p, hlo(A.y), acc2);
            acc3 = fmaf(p, hhi(A.y), acc3);
            acc4 = fmaf(p, hlo(A.z), acc4);
            acc5 = fmaf(p, hhi(A.z), acc5);
            acc6 = fmaf(p, hlo(A.w), acc6);
            acc7 = fmaf(p, hhi(A.w), acc7);
        }
        #undef PAIR2
    }
    float inv = 1.0f / sr;
    float4 bb0 = *(const float4*)&b2[hl * 8];
    float4 bb1 = *(const float4*)&b2[hl * 8 + 4];
    float v0 = acc0 * inv + bb0.x;
    float v1 = acc1 * inv + bb0.y;
    float v2 = acc2 * inv + bb0.z;
    float v3 = acc3 * inv + bb0.w;
    float v4 = acc4 * inv + bb1.x;
    float v5 = acc5 * inv + bb1.y;
    float v6 = acc6 * inv + bb1.z;
    float v7 = acc7 * inv + bb1.w;
    float m = fmaxf(fmaxf(fmaxf(v0, v1), fmaxf(v2, v3)),
                    fmaxf(fmaxf(v4, v5), fmaxf(v6, v7)));
    m = fmaxf(m, __shfl_xor(m, 1));
    m = fmaxf(m, __shfl_xor(m, 2));
    float ss = __expf(v0 - m) + __expf(v1 - m) + __expf(v2 - m) + __expf(v3 - m)
             + __expf(v4 - m) + __expf(v5 - m) + __expf(v6 - m) + __expf(v7 - m);
    ss += __shfl_xor(ss, 1);
    ss += __shfl_xor(ss, 2);
    float lg = m + logf(ss);
    float* yr = &y[(size_t)node * OUT_C + hl * 8];
    *(float4*)yr       = make_float4(v0 - lg, v1 - lg, v2 - lg, v3 - lg);
    *(float4*)(yr + 4) = make_float4(v4 - lg, v5 - lg, v6 - lg, v7 - lg);
}

extern "C" void kernel_launch(void* const* d_in, const int* in_sizes, int n_in,
                              void* d_out, int out_size, void* d_ws, size_t ws_size,
                              hipStream_t stream) {
    const float* x    = (const float*)d_in[0];
    const int*   ei   = (const int*)d_in[1];
    const float* W1   = (const float*)d_in[2];
    const float* as1w = (const float*)d_in[3];
    const float* ad1w = (const float*)d_in[4];
    const float* b1   = (const float*)d_in[5];
    const float* W2   = (const float*)d_in[6];
    const float* as2w = (const float*)d_in[7];
    const float* ad2w = (const float*)d_in[8];
    const float* b2   = (const float*)d_in[9];
    float* out = (float*)d_out;

    int n  = in_sizes[0] / IN_C;
    int E_ = in_sizes[1] / 2;
    int EE = E_ + n;

    int NB = (n + (1 << SH) - 1) >> SH;        // buckets (<=512 for n<=131072)
    int NC = (EE + CHA - 1) / CHA;             // chunks
    int M  = NB * NC;
    int NBLK = (M + SCB - 1) / SCB;            // scan blocks (<=32 here)

    char* w = (char*)d_ws;
    size_t off = 0;
    auto take = [&](size_t elems) { void* p = w + off; off += ((elems * 4 + 255) & ~(size_t)255); return p; };
    int* bmat      = (int*)take((size_t)M);
    int* bsums     = (int*)take(256);
    uint4* bfg     = (uint4*)take(8192);       // 32 KB packed W1 fragments
    unsigned* recs = (unsigned*)take((size_t)EE);
    int* row_off   = (int*)take((size_t)n + 1);
    int* csr       = (int*)take((size_t)EE);
    float* as1     = (float*)take((size_t)n * 4);
    float* ad1     = (float*)take((size_t)n * 4);
    unsigned short* h1h = (unsigned short*)take((size_t)n * 64);  // n*128 fp16
    unsigned short* h2h = (unsigned short*)take((size_t)n * 16);  // n*32 fp16
    float* as2     = (float*)take((size_t)n);
    float* ad2     = (float*)take((size_t)n);

    // pre-pass: W1 -> packed MFMA B fragments (once)
    k_prepW<<<8, 256, 0, stream>>>(W1, bfg);

    // fused: bhist (blocks 0..NC-1) + MFMA layer-1 GEMM (rest)
    int ntile = (n + 63) / 64;
    k_gemm1m<<<NC + ntile, 256, 0, stream>>>(x, bfg, as1w, ad1w, ei, bmat,
                                             h1h, as1, ad1, n, E_, NB, NC);

    // CSR build (bucketed counting sort; scanB folded into consumers)
    k_scanA   <<<NBLK, 256, 0, stream>>>(bmat, bsums, M);
    k_bscatter<<<NC, 256, 0, stream>>>(ei, bmat, bsums, recs, E_, n, NB, NC, NBLK);
    k_bfill   <<<NB, 256, 0, stream>>>(recs, bmat, bsums, row_off, csr, n, NB, NC, EE, NBLK);

    // fused layer-1 GAT + layer-2 GEMM (z stays on-chip)
    int gG = (n + 15) / 16;
    k_gat1<<<gG, 256, 0, stream>>>(row_off, csr, as1, ad1, h1h, b1,
                                   W2, as2w, ad2w, h2h, as2, ad2, n);

    // layer-2 GAT + log_softmax
    int gG2 = (n + 63) / 64;
    k_gat2<<<gG2, 256, 0, stream>>>(row_off, csr, as2, ad2, h2h, b2, out, n);
}

// Round 16
// 278.672 us; speedup vs baseline: 1.0297x; 1.0061x over previous
//
#include <hip/hip_runtime.h>
#include <hip/hip_fp16.h>
#include <math.h>

#define IN_C   128
#define HEADS  4
#define F1     128   // HEADS*HID
#define OUT_C  32
#define NEG    0.2f
#define SH     8     // bucket = dst >> SH (256 dsts per bucket); needs n <= 2^17
#define CHA    8192  // edges per chunk in CSR pass A
#define SCB    4096  // elements per scan block (256 thr x 16)

// ---- fp16 helpers (RNE) ----
__device__ __forceinline__ unsigned short f2h(float f) {
    return __half_as_ushort(__float2half_rn(f));
}
__device__ __forceinline__ float h2f(unsigned short u) {
    return __half2float(__ushort_as_half(u));
}
__device__ __forceinline__ float hlo(unsigned u) { return h2f((unsigned short)(u & 0xffffu)); }
__device__ __forceinline__ float hhi(unsigned u) { return h2f((unsigned short)(u >> 16)); }
__device__ __forceinline__ unsigned pk2(float a, float b) {
    return (unsigned)f2h(a) | ((unsigned)f2h(b) << 16);
}
typedef _Float16 h2v  __attribute__((ext_vector_type(2)));
typedef _Float16 f16x4v __attribute__((ext_vector_type(4)));
typedef _Float16 f16x8v __attribute__((ext_vector_type(8)));
typedef float    f32x4v __attribute__((ext_vector_type(4)));
__device__ __forceinline__ h2v u2h2(unsigned u) {
    h2v r; __builtin_memcpy(&r, &u, 4); return r;
}
__device__ __forceinline__ f16x8v u2h8(uint4 u) {
    f16x8v r; __builtin_memcpy(&r, &u, 16); return r;
}
__device__ __forceinline__ float dot2(unsigned a, unsigned b, float c) {
    return __builtin_amdgcn_fdot2(u2h2(a), u2h2(b), c, false);
}
// v_perm: D = (A.lo16, B.lo16) with perm(B, A, PERM_LO)  [A -> low half]
#define PERM_LO 0x05040100u
#define PERM_HI 0x07060302u
__device__ __forceinline__ float pdot(unsigned b, unsigned a, unsigned sel, h2v pv, float c) {
    return __builtin_amdgcn_fdot2(u2h2(__builtin_amdgcn_perm(b, a, sel)), pv, c, false);
}

// ============ pre-pass: W1 -> packed B fragments + permuted bias table =======
// h1h LAYOUT (fragment-major, per node = 4 heads x 16 words):
//   word cl of head h = packed fp16 (ch 32h+cl, ch 32h+16+cl).
// gat1 lane hl reads words hl*4..hl*4+3 -> acc j holds channel
//   ch(hl,j) = 32*(hl>>2) + (j&1 ? 16 : 0) + (hl&3)*4 + (j>>1).
// b1p[hl*8+j] = b1[ch(hl,j)] so gat1's bias loads stay code-identical.
__global__ __launch_bounds__(256) void k_prepW(
    const float* __restrict__ W, const float* __restrict__ b1,
    uint4* __restrict__ bfg, float* __restrict__ b1p)
{
    int i = blockIdx.x * 256 + threadIdx.x;   // frag-lane id, 2048 total
    if (blockIdx.x == 0 && threadIdx.x < 128) {
        int hl = threadIdx.x >> 3, j = threadIdx.x & 7;
        int ch = 32 * (hl >> 2) + ((j & 1) ? 16 : 0) + (hl & 3) * 4 + (j >> 1);
        b1p[threadIdx.x] = b1[ch];
    }
    if (i >= 2048) return;
    int f = i >> 6, l = i & 63;
    int s = f >> 3, ct = f & 7;
    int col = ct * 16 + (l & 15);
    int k0 = s * 32 + (l >> 4) * 8;
    const float* wp = &W[(size_t)k0 * 128 + col];
    unsigned short u0 = f2h(wp[0]);
    unsigned short u1 = f2h(wp[128]);
    unsigned short u2 = f2h(wp[256]);
    unsigned short u3 = f2h(wp[384]);
    unsigned short u4 = f2h(wp[512]);
    unsigned short u5 = f2h(wp[640]);
    unsigned short u6 = f2h(wp[768]);
    unsigned short u7 = f2h(wp[896]);
    uint4 p;
    p.x = (unsigned)u0 | ((unsigned)u1 << 16);
    p.y = (unsigned)u2 | ((unsigned)u3 << 16);
    p.z = (unsigned)u4 | ((unsigned)u5 << 16);
    p.w = (unsigned)u6 | ((unsigned)u7 << 16);
    bfg[i] = p;
}

// ============ fused: CSR pass A1 (bucket histogram) ∥ layer-1 MFMA GEMM ======
// blockIdx < NC  -> bhist role; else -> gemm role (h1 = x@W1 via MFMA).
// B fragments read directly from global bfg (L2-hot). h1 stored DIRECTLY from
// registers in fragment-major layout: 16 x 4B stores/lane, wave = 4 x 64B full
// sectors. No LDS writeback, no extra barrier.
__global__ __launch_bounds__(256) void k_gemm1m(
    const float* __restrict__ x, const uint4* __restrict__ bfg,
    const float* __restrict__ as_w, const float* __restrict__ ad_w,
    const int* __restrict__ ei, int* __restrict__ bmat,
    unsigned short* __restrict__ h1h, float* __restrict__ as1,
    float* __restrict__ ad1, int n, int E_, int NB, int NC)
{
    __shared__ char lds[16384];
    int t = threadIdx.x;

    if ((int)blockIdx.x < NC) {          // ---- bhist role ----
        int* h = (int*)lds;
        int c = blockIdx.x;
        for (int i = t; i < NB; i += 256) h[i] = 0;
        __syncthreads();
        int e0 = c * CHA, e1 = min(e0 + CHA, E_ + n);
        for (int e = e0 + t; e < e1; e += 256) {
            int d = (e < E_) ? ei[E_ + e] : e - E_;
            atomicAdd(&h[d >> SH], 1);
        }
        __syncthreads();
        for (int i = t; i < NB; i += 256) bmat[i * NC + c] = h[i];
        return;
    }

    // ---- gemm role ----
    char* xhB = lds;               // 16 KB: x tile [64 rows][128 f16], XOR-swizzled
    int n0 = ((int)blockIdx.x - NC) * 64;

    // stage x tile fp16 (coalesced float4 reads, vector 8B LDS stores)
    for (int i = t; i < 64 * 32; i += 256) {
        int node = i >> 5, k4 = (i & 31) * 4;
        int nn = n0 + node;
        float4 v = (nn < n) ? *(const float4*)&x[(size_t)nn * 128 + k4]
                            : make_float4(0.f, 0.f, 0.f, 0.f);
        f16x4v hv = { (_Float16)v.x, (_Float16)v.y, (_Float16)v.z, (_Float16)v.w };
        *(f16x4v*)(xhB + node * 256 + ((2 * k4) ^ ((node & 7) << 4))) = hv;
    }
    __syncthreads();

    int w = t >> 6, l = t & 63, g = l >> 4, cl = l & 15;
    int arow = w * 16 + cl;            // A row (local) for this lane
    f32x4v acc[8] = {};
    #pragma unroll
    for (int s = 0; s < 4; ++s) {
        int k2 = 2 * (s * 32 + g * 8);
        f16x8v a = *(f16x8v*)(xhB + arow * 256 + (k2 ^ ((arow & 7) << 4)));
        #pragma unroll
        for (int ct = 0; ct < 8; ++ct) {
            f16x8v b = u2h8(bfg[(s * 8 + ct) * 64 + l]);   // L2-hit, 1 KB/wave
            acc[ct] = __builtin_amdgcn_mfma_f32_16x16x32_f16(a, b, acc[ct], 0, 0, 0);
        }
    }

    // fused attention partials (D: col=lane&15, row=g*4+r) — R8-verified
    #pragma unroll
    for (int h = 0; h < 4; ++h) {
        float asw0 = as_w[h * 32 + cl],      adw0 = ad_w[h * 32 + cl];
        float asw1 = as_w[h * 32 + 16 + cl], adw1 = ad_w[h * 32 + 16 + cl];
        float ps[4], pd[4];
        #pragma unroll
        for (int r = 0; r < 4; ++r) {
            ps[r] = acc[2 * h][r] * asw0 + acc[2 * h + 1][r] * asw1;
            pd[r] = acc[2 * h][r] * adw0 + acc[2 * h + 1][r] * adw1;
        }
        #pragma unroll
        for (int o = 1; o < 16; o <<= 1) {
            #pragma unroll
            for (int r = 0; r < 4; ++r) {
                ps[r] += __shfl_xor(ps[r], o);
                pd[r] += __shfl_xor(pd[r], o);
            }
        }
        if (cl == h) {
            #pragma unroll
            for (int r = 0; r < 4; ++r) {
                int node = n0 + w * 16 + g * 4 + r;
                if (node < n) {
                    as1[(size_t)node * 4 + h] = ps[r];
                    ad1[(size_t)node * 4 + h] = pd[r];
                }
            }
        }
    }

    // DIRECT fragment-major h1 store: word cl of head h = (ch 32h+cl, 32h+16+cl)
    #pragma unroll
    for (int h = 0; h < 4; ++h) {
        #pragma unroll
        for (int r = 0; r < 4; ++r) {
            int node = n0 + w * 16 + g * 4 + r;
            if (node < n) {
                unsigned wd = pk2(acc[2 * h][r], acc[2 * h + 1][r]);
                *(unsigned*)&h1h[(size_t)node * 128 + h * 32 + cl * 2] = wd;
            }
        }
    }
}

// ============ CSR pass A2: parallel exclusive scan of bmat ===================
__global__ __launch_bounds__(256) void k_scanA(
    int* __restrict__ bmat, int* __restrict__ bsums, int M)
{
    __shared__ int sm[256];
    int t = threadIdx.x;
    int base = blockIdx.x * SCB + t * 16;
    int v[16];
    int s = 0;
    #pragma unroll
    for (int j = 0; j < 16; ++j) {
        int i = base + j;
        v[j] = (i < M) ? bmat[i] : 0;
        s += v[j];
    }
    sm[t] = s;
    __syncthreads();
    for (int off = 1; off < 256; off <<= 1) {
        int a = (t >= off) ? sm[t - off] : 0;
        __syncthreads();
        sm[t] += a;
        __syncthreads();
    }
    int excl = sm[t] - s;
    #pragma unroll
    for (int j = 0; j < 16; ++j) {
        int i = base + j;
        if (i < M) bmat[i] = excl;
        excl += v[j];
    }
    if (t == 255) bsums[blockIdx.x] = sm[255];
}

// ============ CSR pass A3: scatter packed recs into (bucket,chunk) ranges =====
__global__ __launch_bounds__(256) void k_bscatter(
    const int* __restrict__ ei, const int* __restrict__ bmat,
    const int* __restrict__ bsums, unsigned* __restrict__ recs,
    int E_, int n, int NB, int NC, int NBLK)
{
    __shared__ int cur[512];
    __shared__ int pref[32];
    int t = threadIdx.x, c = blockIdx.x;
    if (t < 32) {                     // exclusive prefix of bsums (<=32 entries)
        int v0 = (t < NBLK) ? bsums[t] : 0;
        int v = v0;
        #pragma unroll
        for (int o = 1; o < 32; o <<= 1) {
            int u = __shfl_up(v, o);
            if (t >= o) v += u;
        }
        pref[t] = v - v0;
    }
    __syncthreads();
    for (int i = t; i < NB; i += 256) {
        int m = i * NC + c;
        cur[i] = bmat[m] + pref[m >> 12];
    }
    __syncthreads();
    int e0 = c * CHA, e1 = min(e0 + CHA, E_ + n);
    for (int e = e0 + t; e < e1; e += 256) {
        int s, d;
        if (e < E_) { s = ei[e]; d = ei[E_ + e]; } else { s = d = e - E_; }
        int b = d >> SH;
        int p = atomicAdd(&cur[b], 1);   // LDS atomic
        recs[p] = ((unsigned)(d & ((1 << SH) - 1)) << 17) | (unsigned)s;
    }
}

// ============ CSR pass B: per-bucket fine fill (one block owns one bucket) ====
__global__ __launch_bounds__(256) void k_bfill(
    const unsigned* __restrict__ recs, const int* __restrict__ bmat,
    const int* __restrict__ bsums, int* __restrict__ row_off,
    int* __restrict__ csr, int n, int NB, int NC, int EE, int NBLK)
{
    __shared__ int deg[256];
    __shared__ int cur[256];
    __shared__ int pref[32];
    int t = threadIdx.x, b = blockIdx.x;
    if (t < 32) {
        int v0 = (t < NBLK) ? bsums[t] : 0;
        int v = v0;
        #pragma unroll
        for (int o = 1; o < 32; o <<= 1) {
            int u = __shfl_up(v, o);
            if (t >= o) v += u;
        }
        pref[t] = v - v0;
    }
    deg[t] = 0;
    __syncthreads();
    int m0 = b * NC;
    int r0 = bmat[m0] + pref[m0 >> 12];
    int r1 = EE;
    if (b + 1 < NB) {
        int m1 = (b + 1) * NC;
        r1 = bmat[m1] + pref[m1 >> 12];
    }
    for (int i = r0 + t; i < r1; i += 256)
        atomicAdd(&deg[recs[i] >> 17], 1);
    __syncthreads();
    int v = deg[t];
    for (int off = 1; off < 256; off <<= 1) {
        int a = (t >= off) ? deg[t - off] : 0;
        __syncthreads();
        deg[t] += a;
        __syncthreads();
    }
    int excl = deg[t] - v;
    int dst = (b << SH) + t;
    if (dst < n) row_off[dst] = r0 + excl;
    cur[t] = excl;
    if (b == NB - 1 && t == 0) row_off[n] = EE;
    __syncthreads();
    for (int i = r0 + t; i < r1; i += 256) {
        unsigned rec = recs[i];
        int dl = rec >> 17;
        int p = atomicAdd(&cur[dl], 1);   // LDS atomic
        csr[r0 + p] = (int)(rec & 0x1FFFFu);
    }
}

// ====== fused layer-1 GAT + layer-2 GEMM: softmax/gather/ELU + h2=z@W2 =======
// Gather addresses unchanged (lane hl reads 16B at byte hl*16 of the row);
// fragment-major h1 layout means acc j = channel ch(hl,j) (see k_prepW).
// Bias via permuted b1p; zrow packing remapped to (2k,2k+1) channel words.
__global__ __launch_bounds__(256) void k_gat1(
    const int* __restrict__ row_off, const int* __restrict__ csr,
    const float* __restrict__ as1, const float* __restrict__ ad1,
    const unsigned short* __restrict__ h1h, const float* __restrict__ b1p,
    const float* __restrict__ W2, const float* __restrict__ as2w,
    const float* __restrict__ ad2w, unsigned short* __restrict__ h2h,
    float* __restrict__ as2, float* __restrict__ ad2, int n)
{
    __shared__ int      s_src[16][36];     // 2.25 KB, byte offsets
    __shared__ unsigned s_pw[16][4][17];   // 4.25 KB, [node][head][pair-word]
    __shared__ unsigned W2s[64 * 32];      // 8 KB, [k2][col] packed pairs
    __shared__ unsigned zs[16][66];        // 4.1 KB, z rows packed (pad 66)
    int t = threadIdx.x;

    for (int i = t; i < 64 * 8; i += 256) {
        int k2 = i >> 3, c4 = (i & 7) * 4;
        float4 a = *(const float4*)&W2[(2 * k2) * 32 + c4];
        float4 b = *(const float4*)&W2[(2 * k2 + 1) * 32 + c4];
        uint4 p;
        p.x = pk2(a.x, b.x); p.y = pk2(a.y, b.y);
        p.z = pk2(a.z, b.z); p.w = pk2(a.w, b.w);
        *(uint4*)&W2s[k2 * 32 + c4] = p;
    }
    __syncthreads();

    int nb = t >> 4;                // node slot in block (0..15)
    int hl = t & 15;                // lane within node
    int node = blockIdx.x * 16 + nb;
    if (node < n) {
        int* ssrc = s_src[nb];
        unsigned (*spw)[17] = s_pw[nb];

        const char* h1b = (const char*)h1h;
        int chb  = hl << 4;         // byte offset of my 4 words (16 B)
        int head = hl >> 2;         // my head (all 8 half-channels)

        float4 addv = *(const float4*)&ad1[(size_t)node * 4];
        int beg = row_off[node], end = row_off[node + 1];

        float sr0 = 0.f, sr1 = 0.f, sr2 = 0.f, sr3 = 0.f;
        float acc0 = 0.f, acc1 = 0.f, acc2 = 0.f, acc3 = 0.f;
        float acc4 = 0.f, acc5 = 0.f, acc6 = 0.f, acc7 = 0.f;

        for (int c = beg; c < end; c += 32) {
            int cnt = min(32, end - c);
            int e0 = hl << 1;       // this lane's 2 edges
            float ls0 = 0.f, ls1 = 0.f, ls2 = 0.f, ls3 = 0.f;
            if (e0 < cnt) {
                int sA = csr[c + e0];
                ssrc[e0] = sA << 8;
                float4 avA = *(const float4*)(as1 + ((unsigned)sA << 2));
                float v;
                unsigned short qa0, qa1, qa2, qa3;
                unsigned short qb0 = 0, qb1 = 0, qb2 = 0, qb3 = 0;
                v = avA.x + addv.x; v = v > 0.f ? v : NEG * v; qa0 = f2h(__expf(fminf(v, 10.f)));
                v = avA.y + addv.y; v = v > 0.f ? v : NEG * v; qa1 = f2h(__expf(fminf(v, 10.f)));
                v = avA.z + addv.z; v = v > 0.f ? v : NEG * v; qa2 = f2h(__expf(fminf(v, 10.f)));
                v = avA.w + addv.w; v = v > 0.f ? v : NEG * v; qa3 = f2h(__expf(fminf(v, 10.f)));
                if (e0 + 1 < cnt) {
                    int sB = csr[c + e0 + 1];
                    ssrc[e0 + 1] = sB << 8;
                    float4 avB = *(const float4*)(as1 + ((unsigned)sB << 2));
                    v = avB.x + addv.x; v = v > 0.f ? v : NEG * v; qb0 = f2h(__expf(fminf(v, 10.f)));
                    v = avB.y + addv.y; v = v > 0.f ? v : NEG * v; qb1 = f2h(__expf(fminf(v, 10.f)));
                    v = avB.z + addv.z; v = v > 0.f ? v : NEG * v; qb2 = f2h(__expf(fminf(v, 10.f)));
                    v = avB.w + addv.w; v = v > 0.f ? v : NEG * v; qb3 = f2h(__expf(fminf(v, 10.f)));
                }
                spw[0][hl] = (unsigned)qa0 | ((unsigned)qb0 << 16);
                spw[1][hl] = (unsigned)qa1 | ((unsigned)qb1 << 16);
                spw[2][hl] = (unsigned)qa2 | ((unsigned)qb2 << 16);
                spw[3][hl] = (unsigned)qa3 | ((unsigned)qb3 << 16);
                ls0 = h2f(qa0) + h2f(qb0);
                ls1 = h2f(qa1) + h2f(qb1);
                ls2 = h2f(qa2) + h2f(qb2);
                ls3 = h2f(qa3) + h2f(qb3);
            }
            #pragma unroll
            for (int o = 8; o; o >>= 1) {
                ls0 += __shfl_xor(ls0, o);
                ls1 += __shfl_xor(ls1, o);
                ls2 += __shfl_xor(ls2, o);
                ls3 += __shfl_xor(ls3, o);
            }
            sr0 += ls0; sr1 += ls1; sr2 += ls2; sr3 += ls3;
            __threadfence_block();

            #define MAC8(A, B, pw) {                                          \
                h2v pv = u2h2(pw);                                            \
                acc0 = pdot(B.x, A.x, PERM_LO, pv, acc0);                     \
                acc1 = pdot(B.x, A.x, PERM_HI, pv, acc1);                     \
                acc2 = pdot(B.y, A.y, PERM_LO, pv, acc2);                     \
                acc3 = pdot(B.y, A.y, PERM_HI, pv, acc3);                     \
                acc4 = pdot(B.z, A.z, PERM_LO, pv, acc4);                     \
                acc5 = pdot(B.z, A.z, PERM_HI, pv, acc5);                     \
                acc6 = pdot(B.w, A.w, PERM_LO, pv, acc6);                     \
                acc7 = pdot(B.w, A.w, PERM_HI, pv, acc7);                     \
            }
            int j = 0;
            for (; j + 8 <= cnt; j += 8) {
                int2 o0 = *(const int2*)&ssrc[j];
                int2 o1 = *(const int2*)&ssrc[j + 2];
                int2 o2 = *(const int2*)&ssrc[j + 4];
                int2 o3 = *(const int2*)&ssrc[j + 6];
                int w0 = j >> 1;
                unsigned pw0 = spw[head][w0];
                unsigned pw1 = spw[head][w0 + 1];
                unsigned pw2 = spw[head][w0 + 2];
                unsigned pw3 = spw[head][w0 + 3];
                uint4 A0 = *(const uint4*)(h1b + (unsigned)(o0.x + chb));
                uint4 B0 = *(const uint4*)(h1b + (unsigned)(o0.y + chb));
                uint4 A1 = *(const uint4*)(h1b + (unsigned)(o1.x + chb));
                uint4 B1 = *(const uint4*)(h1b + (unsigned)(o1.y + chb));
                uint4 A2 = *(const uint4*)(h1b + (unsigned)(o2.x + chb));
                uint4 B2 = *(const uint4*)(h1b + (unsigned)(o2.y + chb));
                uint4 A3 = *(const uint4*)(h1b + (unsigned)(o3.x + chb));
                uint4 B3 = *(const uint4*)(h1b + (unsigned)(o3.y + chb));
                MAC8(A0, B0, pw0);
                MAC8(A1, B1, pw1);
                MAC8(A2, B2, pw2);
                MAC8(A3, B3, pw3);
            }
            for (; j + 2 <= cnt; j += 2) {
                int2 oo = *(const int2*)&ssrc[j];
                unsigned pw = spw[head][j >> 1];
                uint4 A = *(const uint4*)(h1b + (unsigned)(oo.x + chb));
                uint4 B = *(const uint4*)(h1b + (unsigned)(oo.y + chb));
                MAC8(A, B, pw);
            }
            if (j < cnt) {
                int o0 = ssrc[j];
                float p = hlo(spw[head][j >> 1]);
                uint4 A = *(const uint4*)(h1b + (unsigned)(o0 + chb));
                acc0 = fmaf(p, hlo(A.x), acc0);
                acc1 = fmaf(p, hhi(A.x), acc1);
                acc2 = fmaf(p, hlo(A.y), acc2);
                acc3 = fmaf(p, hhi(A.y), acc3);
                acc4 = fmaf(p, hlo(A.z), acc4);
                acc5 = fmaf(p, hhi(A.z), acc5);
                acc6 = fmaf(p, hlo(A.w), acc6);
                acc7 = fmaf(p, hhi(A.w), acc7);
            }
            #undef MAC8
        }
        float srh = head == 0 ? sr0 : head == 1 ? sr1 : head == 2 ? sr2 : sr3;
        float inv = 1.0f / srh;
        float4 bb0 = *(const float4*)&b1p[hl * 8];
        float4 bb1 = *(const float4*)&b1p[hl * 8 + 4];
        float v0 = acc0 * inv + bb0.x;
        float v1 = acc1 * inv + bb0.y;
        float v2 = acc2 * inv + bb0.z;
        float v3 = acc3 * inv + bb0.w;
        float v4 = acc4 * inv + bb1.x;
        float v5 = acc5 * inv + bb1.y;
        float v6 = acc6 * inv + bb1.z;
        float v7 = acc7 * inv + bb1.w;
        v0 = v0 > 0.f ? v0 : (__expf(v0) - 1.f);
        v1 = v1 > 0.f ? v1 : (__expf(v1) - 1.f);
        v2 = v2 > 0.f ? v2 : (__expf(v2) - 1.f);
        v3 = v3 > 0.f ? v3 : (__expf(v3) - 1.f);
        v4 = v4 > 0.f ? v4 : (__expf(v4) - 1.f);
        v5 = v5 > 0.f ? v5 : (__expf(v5) - 1.f);
        v6 = v6 > 0.f ? v6 : (__expf(v6) - 1.f);
        v7 = v7 > 0.f ? v7 : (__expf(v7) - 1.f);

        // ---- fused layer-2 GEMM epilogue: h2 = z @ W2 (z never hits HBM) ----
        // lane channels: vA = {v0,v2,v4,v6} = ch 32h+w0.. ; vB = {v1,v3,v5,v7}
        // = ch 32h+16+w0.. ; pack into (2k,2k+1) channel words of zrow.
        unsigned* zrow = zs[nb];
        int zbase = (hl >> 2) * 16 + (hl & 3) * 2;
        zrow[zbase]     = pk2(v0, v2);
        zrow[zbase + 1] = pk2(v4, v6);
        zrow[zbase + 8] = pk2(v1, v3);
        zrow[zbase + 9] = pk2(v5, v7);
        __threadfence_block();
        int c0 = hl * 2;            // my 2 output columns
        float a0 = 0.f, a1 = 0.f;
        #pragma unroll 8
        for (int k2 = 0; k2 < 64; ++k2) {
            unsigned zp = zrow[k2];
            uint2 wp = *(const uint2*)&W2s[k2 * 32 + c0];
            a0 = dot2(zp, wp.x, a0);
            a1 = dot2(zp, wp.y, a1);
        }
        *(unsigned*)&h2h[(size_t)node * 32 + c0] = pk2(a0, a1);
        float2 asw = *(const float2*)&as2w[c0];
        float2 adw = *(const float2*)&ad2w[c0];
        float sa = a0 * asw.x + a1 * asw.y;
        float sd = a0 * adw.x + a1 * adw.y;
        #pragma unroll
        for (int o = 8; o; o >>= 1) {
            sa += __shfl_xor(sa, o);
            sd += __shfl_xor(sd, o);
        }
        if (hl == 0) { as2[node] = sa; ad2[node] = sd; }
    }
}

// ============ fused layer-2 GAT + log_softmax: 4 lanes/node, 64 nodes/block ===
__global__ __launch_bounds__(256) void k_gat2(
    const int* __restrict__ row_off, const int* __restrict__ csr,
    const float* __restrict__ as2, const float* __restrict__ ad2,
    const unsigned short* __restrict__ h2h, const float* __restrict__ b2,
    float* __restrict__ y, int n)
{
    int nb = threadIdx.x >> 2;      // node slot in block (0..63)
    int hl = threadIdx.x & 3;       // lane within node
    int node = blockIdx.x * 64 + nb;
    if (node >= n) return;
    __shared__ int            s_src[64][34];   // 8.5 KB, row BYTE offsets (src<<6)
    __shared__ unsigned short s_p16[64][34];   // 4.25 KB fp16 p
    int* ssrc = s_src[nb];
    unsigned short* sp16 = s_p16[nb];

    const char* h2b = (const char*)h2h;
    int chb = hl << 4;              // byte offset of my 8 channels (8 * 2B)

    float addv = ad2[node];
    int beg = row_off[node], end = row_off[node + 1];
    float sr = 0.f;
    float acc0 = 0.f, acc1 = 0.f, acc2 = 0.f, acc3 = 0.f;
    float acc4 = 0.f, acc5 = 0.f, acc6 = 0.f, acc7 = 0.f;

    for (int c = beg; c < end; c += 32) {
        int cnt = min(32, end - c);
        int e0 = hl << 3;           // 8 edges per lane
        float ls = 0.f;
        #pragma unroll
        for (int k = 0; k < 8; k += 2) {
            int e = e0 + k;
            if (e < cnt) {
                unsigned short qa, qb = 0;
                int sA = csr[c + e];
                ssrc[e] = sA << 6;  // byte offset of fp16 row (32 ch * 2B)
                float v = as2[(unsigned)sA] + addv;
                v = v > 0.f ? v : NEG * v;
                qa = f2h(__expf(fminf(v, 10.f)));
                if (e + 1 < cnt) {
                    int sB = csr[c + e + 1];
                    ssrc[e + 1] = sB << 6;
                    float w2 = as2[(unsigned)sB] + addv;
                    w2 = w2 > 0.f ? w2 : NEG * w2;
                    qb = f2h(__expf(fminf(w2, 10.f)));
                }
                *(unsigned*)&sp16[e] = (unsigned)qa | ((unsigned)qb << 16);
                ls += h2f(qa) + h2f(qb);
            }
        }
        ls += __shfl_xor(ls, 1);
        ls += __shfl_xor(ls, 2);
        sr += ls;
        __threadfence_block();

        #define PAIR2(j) {                                                    \
            int2 oo = *(const int2*)&ssrc[j];                                 \
            unsigned pp = *(const unsigned*)&sp16[j];                         \
            uint4 A = *(const uint4*)(h2b + (unsigned)(oo.x + chb));          \
            uint4 B = *(const uint4*)(h2b + (unsigned)(oo.y + chb));          \
            h2v pv = u2h2(pp);                                                \
            acc0 = pdot(B.x, A.x, PERM_LO, pv, acc0);                         \
            acc1 = pdot(B.x, A.x, PERM_HI, pv, acc1);                         \
            acc2 = pdot(B.y, A.y, PERM_LO, pv, acc2);                         \
            acc3 = pdot(B.y, A.y, PERM_HI, pv, acc3);                         \
            acc4 = pdot(B.z, A.z, PERM_LO, pv, acc4);                         \
            acc5 = pdot(B.z, A.z, PERM_HI, pv, acc5);                         \
            acc6 = pdot(B.w, A.w, PERM_LO, pv, acc6);                         \
            acc7 = pdot(B.w, A.w, PERM_HI, pv, acc7);                         \
        }
        int jj = 0;
        for (; jj + 4 <= cnt; jj += 4) {
            PAIR2(jj);
            PAIR2(jj + 2);
        }
        if (jj + 2 <= cnt) {
            PAIR2(jj);
            jj += 2;
        }
        if (jj < cnt) {
            int o0 = ssrc[jj];
            float p = h2f(sp16[jj]);
            uint4 A = *(const uint4*)(h2b + (unsigned)(o0 + chb));
            acc0 = fmaf(p, hlo(A.x), acc0);
            acc1 = fmaf(p, hhi(A.x), acc1);
            acc2 = fmaf(p, hlo(A.y), acc2);
            acc3 = fmaf(p, hhi(A.y), acc3);
            acc4 = fmaf(p, hlo(A.z), acc4);
            acc5 = fmaf(p, hhi(A.z), acc5);
            acc6 = fmaf(p, hlo(A.w), acc6);
            acc7 = fmaf(p, hhi(A.w), acc7);
        }
        #undef PAIR2
    }
    float inv = 1.0f / sr;
    float4 bb0 = *(const float4*)&b2[hl * 8];
    float4 bb1 = *(const float4*)&b2[hl * 8 + 4];
    float v0 = acc0 * inv + bb0.x;
    float v1 = acc1 * inv + bb0.y;
    float v2 = acc2 * inv + bb0.z;
    float v3 = acc3 * inv + bb0.w;
    float v4 = acc4 * inv + bb1.x;
    float v5 = acc5 * inv + bb1.y;
    float v6 = acc6 * inv + bb1.z;
    float v7 = acc7 * inv + bb1.w;
    float m = fmaxf(fmaxf(fmaxf(v0, v1), fmaxf(v2, v3)),
                    fmaxf(fmaxf(v4, v5), fmaxf(v6, v7)));
    m = fmaxf(m, __shfl_xor(m, 1));
    m = fmaxf(m, __shfl_xor(m, 2));
    float ss = __expf(v0 - m) + __expf(v1 - m) + __expf(v2 - m) + __expf(v3 - m)
             + __expf(v4 - m) + __expf(v5 - m) + __expf(v6 - m) + __expf(v7 - m);
    ss += __shfl_xor(ss, 1);
    ss += __shfl_xor(ss, 2);
    float lg = m + logf(ss);
    float* yr = &y[(size_t)node * OUT_C + hl * 8];
    *(float4*)yr       = make_float4(v0 - lg, v1 - lg, v2 - lg, v3 - lg);
    *(float4*)(yr + 4) = make_float4(v4 - lg, v5 - lg, v6 - lg, v7 - lg);
}

extern "C" void kernel_launch(void* const* d_in, const int* in_sizes, int n_in,
                              void* d_out, int out_size, void* d_ws, size_t ws_size,
                              hipStream_t stream) {
    const float* x    = (const float*)d_in[0];
    const int*   ei   = (const int*)d_in[1];
    const float* W1   = (const float*)d_in[2];
    const float* as1w = (const float*)d_in[3];
    const float* ad1w = (const float*)d_in[4];
    const float* b1   = (const float*)d_in[5];
    const float* W2   = (const float*)d_in[6];
    const float* as2w = (const float*)d_in[7];
    const float* ad2w = (const float*)d_in[8];
    const float* b2   = (const float*)d_in[9];
    float* out = (float*)d_out;

    int n  = in_sizes[0] / IN_C;
    int E_ = in_sizes[1] / 2;
    int EE = E_ + n;

    int NB = (n + (1 << SH) - 1) >> SH;        // buckets (<=512 for n<=131072)
    int NC = (EE + CHA - 1) / CHA;             // chunks
    int M  = NB * NC;
    int NBLK = (M + SCB - 1) / SCB;            // scan blocks (<=32 here)

    char* w = (char*)d_ws;
    size_t off = 0;
    auto take = [&](size_t elems) { void* p = w + off; off += ((elems * 4 + 255) & ~(size_t)255); return p; };
    int* bmat      = (int*)take((size_t)M);
    int* bsums     = (int*)take(256);
    uint4* bfg     = (uint4*)take(8192);       // 32 KB packed W1 fragments
    float* b1p     = (float*)take(128);        // permuted bias table
    unsigned* recs = (unsigned*)take((size_t)EE);
    int* row_off   = (int*)take((size_t)n + 1);
    int* csr       = (int*)take((size_t)EE);
    float* as1     = (float*)take((size_t)n * 4);
    float* ad1     = (float*)take((size_t)n * 4);
    unsigned short* h1h = (unsigned short*)take((size_t)n * 64);  // n*128 fp16
    unsigned short* h2h = (unsigned short*)take((size_t)n * 16);  // n*32 fp16
    float* as2     = (float*)take((size_t)n);
    float* ad2     = (float*)take((size_t)n);

    // pre-pass: W1 -> packed MFMA B fragments + permuted bias (once)
    k_prepW<<<8, 256, 0, stream>>>(W1, b1, bfg, b1p);

    // fused: bhist (blocks 0..NC-1) + MFMA layer-1 GEMM (rest)
    int ntile = (n + 63) / 64;
    k_gemm1m<<<NC + ntile, 256, 0, stream>>>(x, bfg, as1w, ad1w, ei, bmat,
                                             h1h, as1, ad1, n, E_, NB, NC);

    // CSR build (bucketed counting sort; scanB folded into consumers)
    k_scanA   <<<NBLK, 256, 0, stream>>>(bmat, bsums, M);
    k_bscatter<<<NC, 256, 0, stream>>>(ei, bmat, bsums, recs, E_, n, NB, NC, NBLK);
    k_bfill   <<<NB, 256, 0, stream>>>(recs, bmat, bsums, row_off, csr, n, NB, NC, EE, NBLK);

    // fused layer-1 GAT + layer-2 GEMM (z stays on-chip)
    int gG = (n + 15) / 16;
    k_gat1<<<gG, 256, 0, stream>>>(row_off, csr, as1, ad1, h1h, b1p,
                                   W2, as2w, ad2w, h2h, as2, ad2, n);

    // layer-2 GAT + log_softmax
    int gG2 = (n + 63) / 64;
    k_gat2<<<gG2, 256, 0, stream>>>(row_off, csr, as2, ad2, h2h, b2, out, n);
}